// Round 1
// baseline (1749.467 us; speedup 1.0000x reference)
//
#include <hip/hip_runtime.h>
#include <hip/hip_bf16.h>

#define BSZ 16
#define DCH 384
#define LSP 1024
#define SST 64
#define NEXP 8
#define HID 768
#define NTOK 16384   // BSZ*LSP

// ---- workspace byte offsets (exact-fit overlays, lifetimes checked) ----
#define OFF_X1    0ULL            // 25165824  (dead after k_y)
#define OFF_XN    25165824ULL     // 25165824  (dead after k_h)
#define OFF_BCDT  50331648ULL     // 12582912  (dead after dws conv)
#define OFF_BCDTC 62914560ULL     // 12582912  (Bm/Cm/Am; dead after k_y)
#define OFF_H     75497472ULL     // 1572864   (dead after k_hproj)
#define OFF_X2    77070336ULL     // 25165824  (dead after dwconv2)
#define OFF_META  102236160ULL    // 2 MB
#define OFF_LOGITS (OFF_META)
#define OFF_PROBS  (OFF_META + 524288ULL)
#define OFF_IDX    (OFF_META + 655360ULL)
#define OFF_CNT    (OFF_META + 786432ULL)
#define OFF_FILL   (OFF_META + 786464ULL)
#define OFF_OFFS   (OFF_META + 786496ULL)
#define OFF_LTOK   (OFF_META + 786560ULL)
#define OFF_LP     (OFF_META + 917632ULL)
// overlays (used only after their hosts are dead):
#define OFF_HE    0ULL                      // 32768*768*2 = 50331648 == x1+xn
#define OFF_T16   OFF_BCDT                  // 16384*384*2 = 12582912 exact
#define OFF_W1B   OFF_BCDTC                 // 4718592
#define OFF_W3B   (OFF_BCDTC + 4718592ULL)
#define OFF_W2B   (OFF_BCDTC + 9437184ULL)  // ends exactly at OFF_X2

typedef __attribute__((ext_vector_type(8))) short bf16x8;
typedef __attribute__((ext_vector_type(4))) float f32x4;

__device__ __forceinline__ unsigned short f2bf(float f) {
  union { float f; unsigned int u; } x; x.f = f;
  unsigned int r = (x.u + 0x7fffu + ((x.u >> 16) & 1u)) >> 16;  // RNE
  return (unsigned short)r;
}

// ---------------- depthwise 3x3 (+ optional BN + residual) ----------------
__global__ void k_dwbnres(const float* __restrict__ x, const float* __restrict__ w,
                          const float* __restrict__ g, const float* __restrict__ bb,
                          const float* __restrict__ mm, const float* __restrict__ vv,
                          float* __restrict__ out, int C) {
  int bc = blockIdx.x;
  int c = bc % C;
  __shared__ float tile[34 * 34];
  const float* img = x + (size_t)bc * 1024;
  for (int i = threadIdx.x; i < 34 * 34; i += 256) tile[i] = 0.f;
  __syncthreads();
  for (int i = threadIdx.x; i < 1024; i += 256) {
    int r = i >> 5, cc = i & 31;
    tile[(r + 1) * 34 + (cc + 1)] = img[i];
  }
  __syncthreads();
  float w0 = w[c*9+0], w1 = w[c*9+1], w2 = w[c*9+2], w3 = w[c*9+3], w4 = w[c*9+4],
        w5 = w[c*9+5], w6 = w[c*9+6], w7 = w[c*9+7], w8 = w[c*9+8];
  bool res = (g != nullptr);
  float scale = 1.f, bias = 0.f;
  if (res) { float s = g[c] * rsqrtf(vv[c] + 1e-5f); scale = s; bias = bb[c] - mm[c] * s; }
  for (int i = threadIdx.x; i < 1024; i += 256) {
    int r = i >> 5, cc = i & 31;
    const float* t0 = &tile[r * 34 + cc];
    float acc = t0[0]*w0 + t0[1]*w1 + t0[2]*w2
              + t0[34]*w3 + t0[35]*w4 + t0[36]*w5
              + t0[68]*w6 + t0[69]*w7 + t0[70]*w8;
    float o = res ? (t0[35] + acc * scale + bias) : acc;
    out[(size_t)bc * 1024 + i] = o;
  }
}

// ---------------- LayerNorm over channel dim of (B, D, L) ----------------
__global__ void k_layernorm(const float* __restrict__ x, const float* __restrict__ lw,
                            const float* __restrict__ lb, float* __restrict__ xn) {
  int lane = threadIdx.x & 63;
  int slice = threadIdx.x >> 6;           // 4 slices of 96 channels
  int pos0 = blockIdx.x * 64;             // 64 positions, all same b
  int b = pos0 >> 10;
  int l = (pos0 & 1023) + lane;
  const float* xb = x + (size_t)b * DCH * LSP + l;
  float s = 0.f, s2 = 0.f;
  for (int d = slice * 96; d < slice * 96 + 96; d++) {
    float v = xb[(size_t)d * LSP];
    s += v; s2 += v * v;
  }
  __shared__ float red[2][4][64];
  red[0][slice][lane] = s; red[1][slice][lane] = s2;
  __syncthreads();
  if (slice == 0) {
    s  = red[0][0][lane] + red[0][1][lane] + red[0][2][lane] + red[0][3][lane];
    s2 = red[1][0][lane] + red[1][1][lane] + red[1][2][lane] + red[1][3][lane];
    float mu = s * (1.f / 384.f);
    float var = s2 * (1.f / 384.f) - mu * mu;
    red[0][0][lane] = mu;
    red[1][0][lane] = rsqrtf(var + 1e-5f);
  }
  __syncthreads();
  float mu = red[0][0][lane], rs = red[1][0][lane];
  float* xnb = xn + (size_t)b * DCH * LSP + l;
  for (int d = slice * 96; d < slice * 96 + 96; d++) {
    float v = xb[(size_t)d * LSP];
    xnb[(size_t)d * LSP] = (v - mu) * rs * lw[d] + lb[d];
  }
}

// ---------------- bcdt = bcdt_w(192x384) @ xn(b,384,1024) ----------------
__global__ void k_bcdt(const float* __restrict__ xn, const float* __restrict__ wt,
                       float* __restrict__ out) {
  int lt = blockIdx.x, ct = blockIdx.y, b = blockIdx.z;   // (8, 3, 16)
  __shared__ float wsm[64][33];
  __shared__ float xs[32][129];
  int lg = threadIdx.x & 31, cg = threadIdx.x >> 5;
  float acc[8][4];
  for (int i = 0; i < 8; i++) for (int j = 0; j < 4; j++) acc[i][j] = 0.f;
  const float* xb = xn + (size_t)b * DCH * LSP + lt * 128;
  for (int d0 = 0; d0 < 384; d0 += 32) {
    for (int i = threadIdx.x; i < 2048; i += 256) {
      int c = i >> 5, dd = i & 31;
      wsm[c][dd] = wt[(size_t)(ct * 64 + c) * 384 + d0 + dd];
    }
    for (int i = threadIdx.x; i < 4096; i += 256) {
      int dd = i >> 7, ll = i & 127;
      xs[dd][ll] = xb[(size_t)(d0 + dd) * LSP + ll];
    }
    __syncthreads();
    for (int dd = 0; dd < 32; dd++) {
      float xv[4];
      #pragma unroll
      for (int il = 0; il < 4; il++) xv[il] = xs[dd][lg + 32 * il];
      #pragma unroll
      for (int ic = 0; ic < 8; ic++) {
        float wv = wsm[cg + 8 * ic][dd];
        #pragma unroll
        for (int il = 0; il < 4; il++) acc[ic][il] += wv * xv[il];
      }
    }
    __syncthreads();
  }
  for (int ic = 0; ic < 8; ic++)
    for (int il = 0; il < 4; il++)
      out[(size_t)b * 196608 + (size_t)(ct * 64 + cg + 8 * ic) * 1024 + lt * 128 + lg + 32 * il] = acc[ic][il];
}

// ---------------- softmax over L on dt rows (in place) ----------------
__global__ void k_softmax(float* __restrict__ bc, const float* __restrict__ Av) {
  int b = blockIdx.x >> 6, s = blockIdx.x & 63;
  float* row = bc + (size_t)b * 196608 + (size_t)(128 + s) * 1024;
  float a = Av[s];
  int t = threadIdx.x;
  float v[4]; float mx = -3.0e38f;
  #pragma unroll
  for (int i = 0; i < 4; i++) { v[i] = row[t + 256 * i] + a; mx = fmaxf(mx, v[i]); }
  #pragma unroll
  for (int off = 32; off >= 1; off >>= 1) mx = fmaxf(mx, __shfl_xor(mx, off));
  __shared__ float redm[4], reds[4];
  if ((t & 63) == 0) redm[t >> 6] = mx;
  __syncthreads();
  mx = fmaxf(fmaxf(redm[0], redm[1]), fmaxf(redm[2], redm[3]));
  float sm = 0.f;
  #pragma unroll
  for (int i = 0; i < 4; i++) { v[i] = __expf(v[i] - mx); sm += v[i]; }
  #pragma unroll
  for (int off = 32; off >= 1; off >>= 1) sm += __shfl_xor(sm, off);
  if ((t & 63) == 0) reds[t >> 6] = sm;
  __syncthreads();
  sm = reds[0] + reds[1] + reds[2] + reds[3];
  float inv = 1.f / sm;
  #pragma unroll
  for (int i = 0; i < 4; i++) row[t + 256 * i] = v[i] * inv;
}

// ---------------- h[b,d,s] = sum_l xn[b,d,l] * (Am*Bm)[b,s,l] ----------------
__global__ void k_h(const float* __restrict__ xn, const float* __restrict__ bc,
                    float* __restrict__ h) {
  int dt_ = blockIdx.x, b = blockIdx.y;   // (6, 16)
  __shared__ float xs[64][65];
  __shared__ float ab[64][65];
  int sg = threadIdx.x & 63, dg = threadIdx.x >> 6;
  float acc[16];
  for (int i = 0; i < 16; i++) acc[i] = 0.f;
  const float* Bm = bc + (size_t)b * 196608;
  const float* Am = bc + (size_t)b * 196608 + 131072;
  const float* xb = xn + (size_t)b * DCH * LSP + (size_t)(dt_ * 64) * LSP;
  for (int l0 = 0; l0 < 1024; l0 += 64) {
    for (int i = threadIdx.x; i < 4096; i += 256) {
      int r = i >> 6, ll = i & 63;
      xs[r][ll] = xb[(size_t)r * LSP + l0 + ll];
      ab[r][ll] = Am[(size_t)r * 1024 + l0 + ll] * Bm[(size_t)r * 1024 + l0 + ll];
    }
    __syncthreads();
    for (int ll = 0; ll < 64; ll++) {
      float av = ab[sg][ll];
      #pragma unroll
      for (int id = 0; id < 16; id++) acc[id] += xs[dg + 4 * id][ll] * av;
    }
    __syncthreads();
  }
  for (int id = 0; id < 16; id++)
    h[(size_t)b * DCH * SST + (size_t)(dt_ * 64 + dg + 4 * id) * 64 + sg] = acc[id];
}

// ---------------- h2 = silu(hproj_w(384x384) @ h) ----------------
__global__ void k_hproj(const float* __restrict__ h, const float* __restrict__ pw,
                        float* __restrict__ h2) {
  int et = blockIdx.x, b = blockIdx.y;   // (6, 16)
  __shared__ float hs[64][65];   // [d][s]
  __shared__ float ps[64][65];   // [e][d]
  int sg = threadIdx.x & 63, eg = threadIdx.x >> 6;
  float acc[16];
  for (int i = 0; i < 16; i++) acc[i] = 0.f;
  for (int d0 = 0; d0 < 384; d0 += 64) {
    for (int i = threadIdx.x; i < 4096; i += 256) {
      int r = i >> 6, cc = i & 63;
      hs[r][cc] = h[(size_t)b * DCH * SST + (size_t)(d0 + r) * 64 + cc];
      ps[r][cc] = pw[(size_t)(et * 64 + r) * 384 + d0 + cc];
    }
    __syncthreads();
    for (int dd = 0; dd < 64; dd++) {
      float hv = hs[dd][sg];
      #pragma unroll
      for (int ie = 0; ie < 16; ie++) acc[ie] += ps[eg + 4 * ie][dd] * hv;
    }
    __syncthreads();
  }
  for (int ie = 0; ie < 16; ie++) {
    float v = acc[ie];
    v = v / (1.f + __expf(-v));
    h2[(size_t)b * DCH * SST + (size_t)(et * 64 + eg + 4 * ie) * 64 + sg] = v;
  }
}

// ---------------- x2 = x1 + h2 @ Cm ----------------
__global__ void k_y(const float* __restrict__ h2, const float* __restrict__ bc,
                    const float* __restrict__ x1, float* __restrict__ x2) {
  int lt = blockIdx.x, dt_ = blockIdx.y, b = blockIdx.z;   // (8, 12, 16)
  __shared__ float hss[32][65];
  __shared__ float cs[64][129];
  int lg = threadIdx.x & 31, dg = threadIdx.x >> 5;
  float acc[4][4];
  for (int i = 0; i < 4; i++) for (int j = 0; j < 4; j++) acc[i][j] = 0.f;
  for (int i = threadIdx.x; i < 2048; i += 256) {
    int r = i >> 6, cc = i & 63;
    hss[r][cc] = h2[(size_t)b * DCH * SST + (size_t)(dt_ * 32 + r) * 64 + cc];
  }
  const float* Cm = bc + (size_t)b * 196608 + 65536;
  for (int i = threadIdx.x; i < 8192; i += 256) {
    int ss = i >> 7, ll = i & 127;
    cs[ss][ll] = Cm[(size_t)ss * 1024 + lt * 128 + ll];
  }
  __syncthreads();
  for (int ss = 0; ss < 64; ss++) {
    float cv[4];
    #pragma unroll
    for (int il = 0; il < 4; il++) cv[il] = cs[ss][lg + 32 * il];
    #pragma unroll
    for (int id = 0; id < 4; id++) {
      float hv = hss[dg * 4 + id][ss];
      #pragma unroll
      for (int il = 0; il < 4; il++) acc[id][il] += hv * cv[il];
    }
  }
  size_t base = (size_t)b * DCH * LSP + (size_t)(dt_ * 32) * LSP + lt * 128;
  for (int id = 0; id < 4; id++)
    for (int il = 0; il < 4; il++) {
      size_t o = base + (size_t)(dg * 4 + id) * LSP + lg + 32 * il;
      x2[o] = x1[o] + acc[id][il];
    }
}

// ---------------- router logits ----------------
__global__ void k_router(const float* __restrict__ x3, const float* __restrict__ gw,
                         const float* __restrict__ gb, float* __restrict__ logits) {
  __shared__ float xs[64][65];
  __shared__ float gs[8][64];
  int blk = blockIdx.x;                  // 256 blocks of 64 tokens
  int b = blk >> 4; int l0 = (blk & 15) * 64;
  int lg = threadIdx.x & 63, eg = threadIdx.x >> 6;
  float acc0 = 0.f, acc1 = 0.f;
  const float* xb = x3 + (size_t)b * DCH * LSP + l0;
  for (int d0 = 0; d0 < 384; d0 += 64) {
    for (int i = threadIdx.x; i < 4096; i += 256) {
      int dd = i >> 6, ll = i & 63;
      xs[dd][ll] = xb[(size_t)(d0 + dd) * LSP + ll];
    }
    if (threadIdx.x < 512 && threadIdx.x < 256) {}  // no-op
    for (int i = threadIdx.x; i < 512; i += 256) {
      int e = i >> 6, dd = i & 63;
      gs[e][dd] = gw[(size_t)e * 384 + d0 + dd];
    }
    __syncthreads();
    for (int dd = 0; dd < 64; dd++) {
      float xv = xs[dd][lg];
      acc0 += gs[eg][dd] * xv;
      acc1 += gs[eg + 4][dd] * xv;
    }
    __syncthreads();
  }
  int n = b * 1024 + l0 + lg;
  logits[(size_t)n * 8 + eg]     = acc0 + gb[eg];
  logits[(size_t)n * 8 + eg + 4] = acc1 + gb[eg + 4];
}

// ---------------- top-2 + softmax + counts ----------------
__global__ void k_topk(const float* __restrict__ logits, float* __restrict__ probs,
                       int* __restrict__ idx, int* __restrict__ cnt) {
  int n = blockIdx.x * 256 + threadIdx.x;
  float lv[8];
  for (int e = 0; e < 8; e++) lv[e] = logits[(size_t)n * 8 + e];
  int i1 = 0; float v1 = lv[0];
  for (int e = 1; e < 8; e++) if (lv[e] > v1) { v1 = lv[e]; i1 = e; }
  int i2 = -1; float v2 = -3.0e38f;
  for (int e = 0; e < 8; e++) { if (e == i1) continue; if (lv[e] > v2) { v2 = lv[e]; i2 = e; } }
  float p1 = 1.f / (1.f + __expf(v2 - v1));
  probs[n * 2] = p1; probs[n * 2 + 1] = 1.f - p1;
  idx[n * 2] = i1; idx[n * 2 + 1] = i2;
  atomicAdd(&cnt[i1], 1); atomicAdd(&cnt[i2], 1);
}

__global__ void k_offsets(const int* __restrict__ cnt, int* __restrict__ offs) {
  if (threadIdx.x == 0) { int a = 0; for (int e = 0; e < 8; e++) { offs[e] = a; a += cnt[e]; } }
}

__global__ void k_build(const int* __restrict__ idx, const float* __restrict__ probs,
                        const int* __restrict__ offs, int* __restrict__ fill,
                        int* __restrict__ ltok, float* __restrict__ lp) {
  int n = blockIdx.x * 256 + threadIdx.x;
  for (int s = 0; s < 2; s++) {
    int e = idx[n * 2 + s];
    int pos = offs[e] + atomicAdd(&fill[e], 1);
    ltok[pos] = n; lp[pos] = probs[n * 2 + s];
  }
}

// ---------------- tokens -> bf16 [N][D] (transpose) ----------------
__global__ void k_t16(const float* __restrict__ x3, unsigned short* __restrict__ t16) {
  __shared__ float tl[32][33];
  int lt = blockIdx.x, dt_ = blockIdx.y, b = blockIdx.z;   // (32, 12, 16)
  const float* xb = x3 + (size_t)b * DCH * LSP + (size_t)(dt_ * 32) * LSP + lt * 32;
  for (int i = threadIdx.x; i < 1024; i += 256) {
    int dd = i >> 5, ll = i & 31;
    tl[dd][ll] = xb[(size_t)dd * LSP + ll];
  }
  __syncthreads();
  for (int i = threadIdx.x; i < 1024; i += 256) {
    int ll = i >> 5, dd = i & 31;
    int n = b * 1024 + lt * 32 + ll;
    t16[(size_t)n * 384 + dt_ * 32 + dd] = f2bf(tl[dd][ll]);
  }
}

__global__ void k_f2bf(const float* __restrict__ src, unsigned short* __restrict__ dst, int n) {
  int i = blockIdx.x * 256 + threadIdx.x;
  if (i < n) dst[i] = f2bf(src[i]);
}

// ---------------- MoE GEMM1: he = silu(t@w1^T+b1)*(t@w3^T+b3), bf16 MFMA ----------------
__global__ void __launch_bounds__(256) k_moe1(
    const unsigned short* __restrict__ t16, const unsigned short* __restrict__ w1,
    const unsigned short* __restrict__ w3, const float* __restrict__ b1,
    const float* __restrict__ b3, const int* __restrict__ ltok,
    const int* __restrict__ cnt, const int* __restrict__ offs,
    unsigned short* __restrict__ he, int e) {
  int ne = cnt[e];
  int rt = blockIdx.x;
  if (rt * 64 >= ne) return;
  int ct = blockIdx.y;                  // 12 col tiles of 64 over HID
  int base = offs[e];
  __shared__ unsigned short As[64 * 40], B1s[64 * 40], B3s[64 * 40];
  __shared__ int toks[64];
  int tid = threadIdx.x;
  if (tid < 64) {
    int r = rt * 64 + tid;
    toks[tid] = ltok[base + (r < ne ? r : ne - 1)];
  }
  __syncthreads();
  int lane = tid & 63, wave = tid >> 6;
  int wm = (wave >> 1) * 32, wn = (wave & 1) * 32;
  int fm = lane & 15, fq = lane >> 4;
  f32x4 acc1[2][2] = {{{0.f,0.f,0.f,0.f},{0.f,0.f,0.f,0.f}},{{0.f,0.f,0.f,0.f},{0.f,0.f,0.f,0.f}}};
  f32x4 acc3[2][2] = {{{0.f,0.f,0.f,0.f},{0.f,0.f,0.f,0.f}},{{0.f,0.f,0.f,0.f},{0.f,0.f,0.f,0.f}}};
  int lrow = tid >> 2, lkk = (tid & 3) * 8;
  const unsigned short* w1e = w1 + ((size_t)e * 768 + ct * 64) * 384;
  const unsigned short* w3e = w3 + ((size_t)e * 768 + ct * 64) * 384;
  size_t arow = (size_t)toks[lrow] * 384;
  for (int k0 = 0; k0 < 384; k0 += 32) {
    *(bf16x8*)&As[lrow * 40 + lkk]  = *(const bf16x8*)(t16 + arow + k0 + lkk);
    *(bf16x8*)&B1s[lrow * 40 + lkk] = *(const bf16x8*)(w1e + (size_t)lrow * 384 + k0 + lkk);
    *(bf16x8*)&B3s[lrow * 40 + lkk] = *(const bf16x8*)(w3e + (size_t)lrow * 384 + k0 + lkk);
    __syncthreads();
    #pragma unroll
    for (int mi = 0; mi < 2; mi++) {
      bf16x8 av = *(bf16x8*)&As[(wm + mi * 16 + fm) * 40 + fq * 8];
      #pragma unroll
      for (int ni = 0; ni < 2; ni++) {
        bf16x8 b1v = *(bf16x8*)&B1s[(wn + ni * 16 + fm) * 40 + fq * 8];
        bf16x8 b3v = *(bf16x8*)&B3s[(wn + ni * 16 + fm) * 40 + fq * 8];
        acc1[mi][ni] = __builtin_amdgcn_mfma_f32_16x16x32_bf16(av, b1v, acc1[mi][ni], 0, 0, 0);
        acc3[mi][ni] = __builtin_amdgcn_mfma_f32_16x16x32_bf16(av, b3v, acc3[mi][ni], 0, 0, 0);
      }
    }
    __syncthreads();
  }
  #pragma unroll
  for (int mi = 0; mi < 2; mi++)
    #pragma unroll
    for (int ni = 0; ni < 2; ni++)
      #pragma unroll
      for (int r = 0; r < 4; r++) {
        int lr = wm + mi * 16 + fq * 4 + r;
        int gr = rt * 64 + lr;
        if (gr < ne) {
          int col = ct * 64 + wn + ni * 16 + fm;
          float z1 = acc1[mi][ni][r] + b1[e * 768 + col];
          float z3 = acc3[mi][ni][r] + b3[e * 768 + col];
          float val = (z1 / (1.f + __expf(-z1))) * z3;
          he[((size_t)base + gr) * 768 + col] = f2bf(val);
        }
      }
}

// ---------------- MoE GEMM2: ymoe scatter-add ----------------
__global__ void __launch_bounds__(256) k_moe2(
    const unsigned short* __restrict__ he, const unsigned short* __restrict__ w2,
    const float* __restrict__ b2, const float* __restrict__ lp,
    const int* __restrict__ ltok, const int* __restrict__ cnt,
    const int* __restrict__ offs, float* __restrict__ xout, int e) {
  int ne = cnt[e];
  int rt = blockIdx.x;
  if (rt * 64 >= ne) return;
  int ct = blockIdx.y;                  // 6 col tiles of 64 over D
  int base = offs[e];
  __shared__ unsigned short As[64 * 40], Bs[64 * 40];
  __shared__ int toks[64];
  __shared__ float lps[64];
  int tid = threadIdx.x;
  if (tid < 64) {
    int r = rt * 64 + tid;
    int cl = (r < ne ? r : ne - 1);
    toks[tid] = ltok[base + cl];
    lps[tid] = lp[base + cl];
  }
  int lane = tid & 63, wave = tid >> 6;
  int wm = (wave >> 1) * 32, wn = (wave & 1) * 32;
  int fm = lane & 15, fq = lane >> 4;
  f32x4 acc[2][2] = {{{0.f,0.f,0.f,0.f},{0.f,0.f,0.f,0.f}},{{0.f,0.f,0.f,0.f},{0.f,0.f,0.f,0.f}}};
  int lrow = tid >> 2, lkk = (tid & 3) * 8;
  const unsigned short* Arow = he + ((size_t)base + rt * 64 + lrow) * 768;
  const unsigned short* Brow = w2 + ((size_t)e * 384 + ct * 64 + lrow) * 768;
  for (int k0 = 0; k0 < 768; k0 += 32) {
    *(bf16x8*)&As[lrow * 40 + lkk] = *(const bf16x8*)(Arow + k0 + lkk);
    *(bf16x8*)&Bs[lrow * 40 + lkk] = *(const bf16x8*)(Brow + k0 + lkk);
    __syncthreads();
    #pragma unroll
    for (int mi = 0; mi < 2; mi++) {
      bf16x8 av = *(bf16x8*)&As[(wm + mi * 16 + fm) * 40 + fq * 8];
      #pragma unroll
      for (int ni = 0; ni < 2; ni++) {
        bf16x8 bv = *(bf16x8*)&Bs[(wn + ni * 16 + fm) * 40 + fq * 8];
        acc[mi][ni] = __builtin_amdgcn_mfma_f32_16x16x32_bf16(av, bv, acc[mi][ni], 0, 0, 0);
      }
    }
    __syncthreads();
  }
  #pragma unroll
  for (int mi = 0; mi < 2; mi++)
    #pragma unroll
    for (int ni = 0; ni < 2; ni++)
      #pragma unroll
      for (int r = 0; r < 4; r++) {
        int lr = wm + mi * 16 + fq * 4 + r;
        int gr = rt * 64 + lr;
        if (gr < ne) {
          int col = ct * 64 + wn + ni * 16 + fm;
          float val = (acc[mi][ni][r] + b2[e * 384 + col]) * lps[lr];
          int n = toks[lr];
          int b = n >> 10, l = n & 1023;
          atomicAdd(&xout[(size_t)b * DCH * LSP + (size_t)col * LSP + l], val);
        }
      }
}

extern "C" void kernel_launch(void* const* d_in, const int* in_sizes, int n_in,
                              void* d_out, int out_size, void* d_ws, size_t ws_size,
                              hipStream_t stream) {
  const float* x      = (const float*)d_in[0];
  const float* dw1    = (const float*)d_in[1];
  const float* bn1g   = (const float*)d_in[2];
  const float* bn1b   = (const float*)d_in[3];
  const float* bn1m   = (const float*)d_in[4];
  const float* bn1v   = (const float*)d_in[5];
  const float* dw2    = (const float*)d_in[6];
  const float* bn2g   = (const float*)d_in[7];
  const float* bn2b   = (const float*)d_in[8];
  const float* bn2m   = (const float*)d_in[9];
  const float* bn2v   = (const float*)d_in[10];
  const float* lnw    = (const float*)d_in[11];
  const float* lnb    = (const float*)d_in[12];
  const float* bcdtw  = (const float*)d_in[13];
  const float* dwsw   = (const float*)d_in[14];
  const float* hprojw = (const float*)d_in[15];
  const float* Avec   = (const float*)d_in[16];
  const float* gatew  = (const float*)d_in[17];
  const float* gateb  = (const float*)d_in[18];
  const float* w1f    = (const float*)d_in[19];
  const float* b1f    = (const float*)d_in[20];
  const float* w2f    = (const float*)d_in[21];
  const float* b2f    = (const float*)d_in[22];
  const float* w3f    = (const float*)d_in[23];
  const float* b3f    = (const float*)d_in[24];

  char* wsb = (char*)d_ws;
  float* x1    = (float*)(wsb + OFF_X1);
  float* xn    = (float*)(wsb + OFF_XN);
  float* bcdt  = (float*)(wsb + OFF_BCDT);
  float* bcdtc = (float*)(wsb + OFF_BCDTC);
  float* hbuf  = (float*)(wsb + OFF_H);
  float* x2    = (float*)(wsb + OFF_X2);
  float* logits = (float*)(wsb + OFF_LOGITS);
  float* probs  = (float*)(wsb + OFF_PROBS);
  int*   idx    = (int*)(wsb + OFF_IDX);
  int*   cnt    = (int*)(wsb + OFF_CNT);
  int*   fill   = (int*)(wsb + OFF_FILL);
  int*   offs   = (int*)(wsb + OFF_OFFS);
  int*   ltok   = (int*)(wsb + OFF_LTOK);
  float* lp     = (float*)(wsb + OFF_LP);
  unsigned short* t16 = (unsigned short*)(wsb + OFF_T16);
  unsigned short* w1b = (unsigned short*)(wsb + OFF_W1B);
  unsigned short* w3b = (unsigned short*)(wsb + OFF_W3B);
  unsigned short* w2b = (unsigned short*)(wsb + OFF_W2B);
  unsigned short* he  = (unsigned short*)(wsb + OFF_HE);
  float* xout = (float*)d_out;
  float* h2   = xout + (size_t)BSZ * DCH * LSP;   // second output region

  // stage 1: x1 = x + bn1(dw1(x))
  k_dwbnres<<<BSZ * DCH, 256, 0, stream>>>(x, dw1, bn1g, bn1b, bn1m, bn1v, x1, DCH);
  // stage 2: layernorm -> xn
  k_layernorm<<<NTOK / 64, 256, 0, stream>>>(x1, lnw, lnb, xn);
  // stage 3: bcdt = bcdt_w @ xn
  k_bcdt<<<dim3(8, 3, BSZ), 256, 0, stream>>>(xn, bcdtw, bcdt);
  // stage 4: depthwise conv on bcdt
  k_dwbnres<<<BSZ * 192, 256, 0, stream>>>(bcdt, dwsw, nullptr, nullptr, nullptr, nullptr, bcdtc, 192);
  // stage 5: softmax(dt + A) over L (in place on channels 128..191)
  k_softmax<<<BSZ * SST, 256, 0, stream>>>(bcdtc, Avec);
  // stage 6: h = xn @ (Am*Bm)^T
  k_h<<<dim3(6, BSZ), 256, 0, stream>>>(xn, bcdtc, hbuf);
  // stage 7: h2 = silu(hproj @ h)  (second output)
  k_hproj<<<dim3(6, BSZ), 256, 0, stream>>>(hbuf, hprojw, h2);
  // stage 8: x2 = x1 + h2 @ Cm
  k_y<<<dim3(8, 12, BSZ), 256, 0, stream>>>(h2, bcdtc, x1, x2);
  // stage 9: x3 = x2 + bn2(dw2(x2)) -> d_out
  k_dwbnres<<<BSZ * DCH, 256, 0, stream>>>(x2, dw2, bn2g, bn2b, bn2m, bn2v, xout, DCH);
  // MoE routing
  hipMemsetAsync(wsb + OFF_CNT, 0, 64, stream);   // cnt + fill
  k_router<<<256, 256, 0, stream>>>(xout, gatew, gateb, logits);
  k_topk<<<NTOK / 256, 256, 0, stream>>>(logits, probs, idx, cnt);
  k_offsets<<<1, 64, 0, stream>>>(cnt, offs);
  k_build<<<NTOK / 256, 256, 0, stream>>>(idx, probs, offs, fill, ltok, lp);
  // tokens + weights to bf16
  k_t16<<<dim3(32, 12, BSZ), 256, 0, stream>>>(xout, t16);
  int nw = NEXP * HID * DCH;
  k_f2bf<<<(nw + 255) / 256, 256, 0, stream>>>(w1f, w1b, nw);
  k_f2bf<<<(nw + 255) / 256, 256, 0, stream>>>(w3f, w3b, nw);
  k_f2bf<<<(nw + 255) / 256, 256, 0, stream>>>(w2f, w2b, nw);
  // per-expert GEMMs (empty tiles early-exit)
  for (int e = 0; e < NEXP; e++)
    k_moe1<<<dim3(256, 12), 256, 0, stream>>>(t16, w1b, w3b, b1f, b3f, ltok, cnt, offs, he, e);
  for (int e = 0; e < NEXP; e++)
    k_moe2<<<dim3(256, 6), 256, 0, stream>>>(he, w2b, b2f, lp, ltok, cnt, offs, xout, e);
}

// Round 2
// 689.254 us; speedup vs baseline: 2.5382x; 2.5382x over previous
//
#include <hip/hip_runtime.h>
#include <hip/hip_bf16.h>

#define BSZ 16
#define DCH 384
#define LSP 1024
#define SST 64
#define NEXP 8
#define HID 768
#define NTOK 16384   // BSZ*LSP
#define MOE_MAXT 520 // max row tiles of 64 across experts: 32768/64 + 8

// ---- workspace byte offsets (exact-fit overlays, lifetimes checked) ----
#define OFF_X1    0ULL            // 25165824  (dead after k_y)
#define OFF_XN    25165824ULL     // 25165824  (dead after k_h)
#define OFF_BCDT  50331648ULL     // 12582912  (dead after dws conv)
#define OFF_BCDTC 62914560ULL     // 12582912  (Bm/Cm/Am; dead after k_y)
#define OFF_H     75497472ULL     // 1572864   (dead after k_hproj)
#define OFF_X2    77070336ULL     // 25165824  (dead after dwconv2)
#define OFF_META  102236160ULL    // ~1.2 MB used
#define OFF_LOGITS (OFF_META)                  // 524288
#define OFF_PROBS  (OFF_META +  524288ULL)     // 131072
#define OFF_IDX    (OFF_META +  655360ULL)     // 131072
#define OFF_CNT    (OFF_META +  786432ULL)     // 32
#define OFF_FILL   (OFF_META +  786464ULL)     // 32
#define OFF_OFFS   (OFF_META +  786496ULL)     // 32
#define OFF_TOFF   (OFF_META +  786560ULL)     // 64 (tile prefix, 9 ints)
#define OFF_LTOK   (OFF_META +  786624ULL)     // 131072
#define OFF_LP     (OFF_META +  917696ULL)     // 131072
#define OFF_TPOS   (OFF_META + 1048768ULL)     // 131072 -> ends 1179840
// overlays (used only after their hosts are dead):
#define OFF_HE    0ULL                      // 32768*768*2 = 50331648 == x1+xn
#define OFF_T16   OFF_BCDT                  // 16384*384*2 = 12582912 exact
#define OFF_W1B   OFF_BCDTC                 // 4718592
#define OFF_W3B   (OFF_BCDTC + 4718592ULL)
#define OFF_W2B   (OFF_BCDTC + 9437184ULL)  // ends exactly at OFF_X2
#define OFF_YMOE  OFF_X2                    // 32768*384*2 = 25165824 == x2 exactly

typedef __attribute__((ext_vector_type(8))) short bf16x8;
typedef __attribute__((ext_vector_type(4))) float f32x4;
typedef __attribute__((ext_vector_type(4))) unsigned short u16x4;

__device__ __forceinline__ unsigned short f2bf(float f) {
  union { float f; unsigned int u; } x; x.f = f;
  unsigned int r = (x.u + 0x7fffu + ((x.u >> 16) & 1u)) >> 16;  // RNE
  return (unsigned short)r;
}
__device__ __forceinline__ float bf2f(unsigned short s) {
  union { unsigned int u; float f; } x; x.u = ((unsigned int)s) << 16; return x.f;
}

// ---------------- depthwise 3x3 (+ optional BN + residual) ----------------
__global__ void k_dwbnres(const float* __restrict__ x, const float* __restrict__ w,
                          const float* __restrict__ g, const float* __restrict__ bb,
                          const float* __restrict__ mm, const float* __restrict__ vv,
                          float* __restrict__ out, int C) {
  int bc = blockIdx.x;
  int c = bc % C;
  __shared__ float tile[34 * 34];
  const float* img = x + (size_t)bc * 1024;
  for (int i = threadIdx.x; i < 34 * 34; i += 256) tile[i] = 0.f;
  __syncthreads();
  for (int i = threadIdx.x; i < 1024; i += 256) {
    int r = i >> 5, cc = i & 31;
    tile[(r + 1) * 34 + (cc + 1)] = img[i];
  }
  __syncthreads();
  float w0 = w[c*9+0], w1 = w[c*9+1], w2 = w[c*9+2], w3 = w[c*9+3], w4 = w[c*9+4],
        w5 = w[c*9+5], w6 = w[c*9+6], w7 = w[c*9+7], w8 = w[c*9+8];
  bool res = (g != nullptr);
  float scale = 1.f, bias = 0.f;
  if (res) { float s = g[c] * rsqrtf(vv[c] + 1e-5f); scale = s; bias = bb[c] - mm[c] * s; }
  for (int i = threadIdx.x; i < 1024; i += 256) {
    int r = i >> 5, cc = i & 31;
    const float* t0 = &tile[r * 34 + cc];
    float acc = t0[0]*w0 + t0[1]*w1 + t0[2]*w2
              + t0[34]*w3 + t0[35]*w4 + t0[36]*w5
              + t0[68]*w6 + t0[69]*w7 + t0[70]*w8;
    float o = res ? (t0[35] + acc * scale + bias) : acc;
    out[(size_t)bc * 1024 + i] = o;
  }
}

// ---------------- LayerNorm over channel dim of (B, D, L) ----------------
__global__ void k_layernorm(const float* __restrict__ x, const float* __restrict__ lw,
                            const float* __restrict__ lb, float* __restrict__ xn) {
  int lane = threadIdx.x & 63;
  int slice = threadIdx.x >> 6;           // 4 slices of 96 channels
  int pos0 = blockIdx.x * 64;             // 64 positions, all same b
  int b = pos0 >> 10;
  int l = (pos0 & 1023) + lane;
  const float* xb = x + (size_t)b * DCH * LSP + l;
  float s = 0.f, s2 = 0.f;
  for (int d = slice * 96; d < slice * 96 + 96; d++) {
    float v = xb[(size_t)d * LSP];
    s += v; s2 += v * v;
  }
  __shared__ float red[2][4][64];
  red[0][slice][lane] = s; red[1][slice][lane] = s2;
  __syncthreads();
  if (slice == 0) {
    s  = red[0][0][lane] + red[0][1][lane] + red[0][2][lane] + red[0][3][lane];
    s2 = red[1][0][lane] + red[1][1][lane] + red[1][2][lane] + red[1][3][lane];
    float mu = s * (1.f / 384.f);
    float var = s2 * (1.f / 384.f) - mu * mu;
    red[0][0][lane] = mu;
    red[1][0][lane] = rsqrtf(var + 1e-5f);
  }
  __syncthreads();
  float mu = red[0][0][lane], rs = red[1][0][lane];
  float* xnb = xn + (size_t)b * DCH * LSP + l;
  for (int d = slice * 96; d < slice * 96 + 96; d++) {
    float v = xb[(size_t)d * LSP];
    xnb[(size_t)d * LSP] = (v - mu) * rs * lw[d] + lb[d];
  }
}

// ---------------- bcdt = bcdt_w(192x384) @ xn(b,384,1024) ----------------
__global__ void k_bcdt(const float* __restrict__ xn, const float* __restrict__ wt,
                       float* __restrict__ out) {
  int lt = blockIdx.x, ct = blockIdx.y, b = blockIdx.z;   // (8, 3, 16)
  __shared__ float wsm[64][33];
  __shared__ float xs[32][129];
  int lg = threadIdx.x & 31, cg = threadIdx.x >> 5;
  float acc[8][4];
  for (int i = 0; i < 8; i++) for (int j = 0; j < 4; j++) acc[i][j] = 0.f;
  const float* xb = xn + (size_t)b * DCH * LSP + lt * 128;
  for (int d0 = 0; d0 < 384; d0 += 32) {
    for (int i = threadIdx.x; i < 2048; i += 256) {
      int c = i >> 5, dd = i & 31;
      wsm[c][dd] = wt[(size_t)(ct * 64 + c) * 384 + d0 + dd];
    }
    for (int i = threadIdx.x; i < 4096; i += 256) {
      int dd = i >> 7, ll = i & 127;
      xs[dd][ll] = xb[(size_t)(d0 + dd) * LSP + ll];
    }
    __syncthreads();
    for (int dd = 0; dd < 32; dd++) {
      float xv[4];
      #pragma unroll
      for (int il = 0; il < 4; il++) xv[il] = xs[dd][lg + 32 * il];
      #pragma unroll
      for (int ic = 0; ic < 8; ic++) {
        float wv = wsm[cg + 8 * ic][dd];
        #pragma unroll
        for (int il = 0; il < 4; il++) acc[ic][il] += wv * xv[il];
      }
    }
    __syncthreads();
  }
  for (int ic = 0; ic < 8; ic++)
    for (int il = 0; il < 4; il++)
      out[(size_t)b * 196608 + (size_t)(ct * 64 + cg + 8 * ic) * 1024 + lt * 128 + lg + 32 * il] = acc[ic][il];
}

// ---------------- softmax over L on dt rows (in place) ----------------
__global__ void k_softmax(float* __restrict__ bc, const float* __restrict__ Av) {
  int b = blockIdx.x >> 6, s = blockIdx.x & 63;
  float* row = bc + (size_t)b * 196608 + (size_t)(128 + s) * 1024;
  float a = Av[s];
  int t = threadIdx.x;
  float v[4]; float mx = -3.0e38f;
  #pragma unroll
  for (int i = 0; i < 4; i++) { v[i] = row[t + 256 * i] + a; mx = fmaxf(mx, v[i]); }
  #pragma unroll
  for (int off = 32; off >= 1; off >>= 1) mx = fmaxf(mx, __shfl_xor(mx, off));
  __shared__ float redm[4], reds[4];
  if ((t & 63) == 0) redm[t >> 6] = mx;
  __syncthreads();
  mx = fmaxf(fmaxf(redm[0], redm[1]), fmaxf(redm[2], redm[3]));
  float sm = 0.f;
  #pragma unroll
  for (int i = 0; i < 4; i++) { v[i] = __expf(v[i] - mx); sm += v[i]; }
  #pragma unroll
  for (int off = 32; off >= 1; off >>= 1) sm += __shfl_xor(sm, off);
  if ((t & 63) == 0) reds[t >> 6] = sm;
  __syncthreads();
  sm = reds[0] + reds[1] + reds[2] + reds[3];
  float inv = 1.f / sm;
  #pragma unroll
  for (int i = 0; i < 4; i++) row[t + 256 * i] = v[i] * inv;
}

// ---------------- h[b,d,s] = sum_l xn[b,d,l] * (Am*Bm)[b,s,l] ----------------
__global__ void k_h(const float* __restrict__ xn, const float* __restrict__ bc,
                    float* __restrict__ h) {
  int dt_ = blockIdx.x, b = blockIdx.y;   // (6, 16)
  __shared__ float xs[64][65];
  __shared__ float ab[64][65];
  int sg = threadIdx.x & 63, dg = threadIdx.x >> 6;
  float acc[16];
  for (int i = 0; i < 16; i++) acc[i] = 0.f;
  const float* Bm = bc + (size_t)b * 196608;
  const float* Am = bc + (size_t)b * 196608 + 131072;
  const float* xb = xn + (size_t)b * DCH * LSP + (size_t)(dt_ * 64) * LSP;
  for (int l0 = 0; l0 < 1024; l0 += 64) {
    for (int i = threadIdx.x; i < 4096; i += 256) {
      int r = i >> 6, ll = i & 63;
      xs[r][ll] = xb[(size_t)r * LSP + l0 + ll];
      ab[r][ll] = Am[(size_t)r * 1024 + l0 + ll] * Bm[(size_t)r * 1024 + l0 + ll];
    }
    __syncthreads();
    for (int ll = 0; ll < 64; ll++) {
      float av = ab[sg][ll];
      #pragma unroll
      for (int id = 0; id < 16; id++) acc[id] += xs[dg + 4 * id][ll] * av;
    }
    __syncthreads();
  }
  for (int id = 0; id < 16; id++)
    h[(size_t)b * DCH * SST + (size_t)(dt_ * 64 + dg + 4 * id) * 64 + sg] = acc[id];
}

// ---------------- h2 = silu(hproj_w(384x384) @ h) ----------------
__global__ void k_hproj(const float* __restrict__ h, const float* __restrict__ pw,
                        float* __restrict__ h2) {
  int et = blockIdx.x, b = blockIdx.y;   // (6, 16)
  __shared__ float hs[64][65];   // [d][s]
  __shared__ float ps[64][65];   // [e][d]
  int sg = threadIdx.x & 63, eg = threadIdx.x >> 6;
  float acc[16];
  for (int i = 0; i < 16; i++) acc[i] = 0.f;
  for (int d0 = 0; d0 < 384; d0 += 64) {
    for (int i = threadIdx.x; i < 4096; i += 256) {
      int r = i >> 6, cc = i & 63;
      hs[r][cc] = h[(size_t)b * DCH * SST + (size_t)(d0 + r) * 64 + cc];
      ps[r][cc] = pw[(size_t)(et * 64 + r) * 384 + d0 + cc];
    }
    __syncthreads();
    for (int dd = 0; dd < 64; dd++) {
      float hv = hs[dd][sg];
      #pragma unroll
      for (int ie = 0; ie < 16; ie++) acc[ie] += ps[eg + 4 * ie][dd] * hv;
    }
    __syncthreads();
  }
  for (int ie = 0; ie < 16; ie++) {
    float v = acc[ie];
    v = v / (1.f + __expf(-v));
    h2[(size_t)b * DCH * SST + (size_t)(et * 64 + eg + 4 * ie) * 64 + sg] = v;
  }
}

// ---------------- x2 = x1 + h2 @ Cm ----------------
__global__ void k_y(const float* __restrict__ h2, const float* __restrict__ bc,
                    const float* __restrict__ x1, float* __restrict__ x2) {
  int lt = blockIdx.x, dt_ = blockIdx.y, b = blockIdx.z;   // (8, 12, 16)
  __shared__ float hss[32][65];
  __shared__ float cs[64][129];
  int lg = threadIdx.x & 31, dg = threadIdx.x >> 5;
  float acc[4][4];
  for (int i = 0; i < 4; i++) for (int j = 0; j < 4; j++) acc[i][j] = 0.f;
  for (int i = threadIdx.x; i < 2048; i += 256) {
    int r = i >> 6, cc = i & 63;
    hss[r][cc] = h2[(size_t)b * DCH * SST + (size_t)(dt_ * 32 + r) * 64 + cc];
  }
  const float* Cm = bc + (size_t)b * 196608 + 65536;
  for (int i = threadIdx.x; i < 8192; i += 256) {
    int ss = i >> 7, ll = i & 127;
    cs[ss][ll] = Cm[(size_t)ss * 1024 + lt * 128 + ll];
  }
  __syncthreads();
  for (int ss = 0; ss < 64; ss++) {
    float cv[4];
    #pragma unroll
    for (int il = 0; il < 4; il++) cv[il] = cs[ss][lg + 32 * il];
    #pragma unroll
    for (int id = 0; id < 4; id++) {
      float hv = hss[dg * 4 + id][ss];
      #pragma unroll
      for (int il = 0; il < 4; il++) acc[id][il] += hv * cv[il];
    }
  }
  size_t base = (size_t)b * DCH * LSP + (size_t)(dt_ * 32) * LSP + lt * 128;
  for (int id = 0; id < 4; id++)
    for (int il = 0; il < 4; il++) {
      size_t o = base + (size_t)(dg * 4 + id) * LSP + lg + 32 * il;
      x2[o] = x1[o] + acc[id][il];
    }
}

// ---------------- router logits ----------------
__global__ void k_router(const float* __restrict__ x3, const float* __restrict__ gw,
                         const float* __restrict__ gb, float* __restrict__ logits) {
  __shared__ float xs[64][65];
  __shared__ float gs[8][64];
  int blk = blockIdx.x;                  // 256 blocks of 64 tokens
  int b = blk >> 4; int l0 = (blk & 15) * 64;
  int lg = threadIdx.x & 63, eg = threadIdx.x >> 6;
  float acc0 = 0.f, acc1 = 0.f;
  const float* xb = x3 + (size_t)b * DCH * LSP + l0;
  for (int d0 = 0; d0 < 384; d0 += 64) {
    for (int i = threadIdx.x; i < 4096; i += 256) {
      int dd = i >> 6, ll = i & 63;
      xs[dd][ll] = xb[(size_t)(d0 + dd) * LSP + ll];
    }
    for (int i = threadIdx.x; i < 512; i += 256) {
      int e = i >> 6, dd = i & 63;
      gs[e][dd] = gw[(size_t)e * 384 + d0 + dd];
    }
    __syncthreads();
    for (int dd = 0; dd < 64; dd++) {
      float xv = xs[dd][lg];
      acc0 += gs[eg][dd] * xv;
      acc1 += gs[eg + 4][dd] * xv;
    }
    __syncthreads();
  }
  int n = b * 1024 + l0 + lg;
  logits[(size_t)n * 8 + eg]     = acc0 + gb[eg];
  logits[(size_t)n * 8 + eg + 4] = acc1 + gb[eg + 4];
}

// ---------------- top-2 + softmax + counts (LDS-aggregated atomics) ----------------
__global__ void k_topk(const float* __restrict__ logits, float* __restrict__ probs,
                       int* __restrict__ idx, int* __restrict__ cnt) {
  __shared__ int lcnt[8];
  if (threadIdx.x < 8) lcnt[threadIdx.x] = 0;
  __syncthreads();
  int n = blockIdx.x * 256 + threadIdx.x;
  float lv[8];
  for (int e = 0; e < 8; e++) lv[e] = logits[(size_t)n * 8 + e];
  int i1 = 0; float v1 = lv[0];
  for (int e = 1; e < 8; e++) if (lv[e] > v1) { v1 = lv[e]; i1 = e; }
  int i2 = -1; float v2 = -3.0e38f;
  for (int e = 0; e < 8; e++) { if (e == i1) continue; if (lv[e] > v2) { v2 = lv[e]; i2 = e; } }
  float p1 = 1.f / (1.f + __expf(v2 - v1));
  probs[n * 2] = p1; probs[n * 2 + 1] = 1.f - p1;
  idx[n * 2] = i1; idx[n * 2 + 1] = i2;
  atomicAdd(&lcnt[i1], 1); atomicAdd(&lcnt[i2], 1);
  __syncthreads();
  if (threadIdx.x < 8) atomicAdd(&cnt[threadIdx.x], lcnt[threadIdx.x]);
}

__global__ void k_offsets(const int* __restrict__ cnt, int* __restrict__ offs,
                          int* __restrict__ toff) {
  if (threadIdx.x == 0) {
    int a = 0, t = 0;
    for (int e = 0; e < 8; e++) {
      offs[e] = a; toff[e] = t;
      a += cnt[e]; t += (cnt[e] + 63) >> 6;
    }
    toff[8] = t;
  }
}

// ---------------- build expert token lists (LDS-aggregated) ----------------
__global__ void k_build(const int* __restrict__ idx, const float* __restrict__ probs,
                        const int* __restrict__ offs, int* __restrict__ fill,
                        int* __restrict__ ltok, float* __restrict__ lp,
                        int* __restrict__ tpos) {
  __shared__ int lcnt[8], lbase[8];
  if (threadIdx.x < 8) lcnt[threadIdx.x] = 0;
  __syncthreads();
  int n = blockIdx.x * 256 + threadIdx.x;
  int e0 = idx[n * 2], e1 = idx[n * 2 + 1];
  int o0 = atomicAdd(&lcnt[e0], 1);
  int o1 = atomicAdd(&lcnt[e1], 1);
  __syncthreads();
  if (threadIdx.x < 8) lbase[threadIdx.x] = atomicAdd(&fill[threadIdx.x], lcnt[threadIdx.x]);
  __syncthreads();
  int p0 = offs[e0] + lbase[e0] + o0;
  int p1 = offs[e1] + lbase[e1] + o1;
  ltok[p0] = n; lp[p0] = probs[n * 2];     tpos[n * 2] = p0;
  ltok[p1] = n; lp[p1] = probs[n * 2 + 1]; tpos[n * 2 + 1] = p1;
}

// ---------------- tokens -> bf16 [N][D] (transpose) ----------------
__global__ void k_t16(const float* __restrict__ x3, unsigned short* __restrict__ t16) {
  __shared__ float tl[32][33];
  int lt = blockIdx.x, dt_ = blockIdx.y, b = blockIdx.z;   // (32, 12, 16)
  const float* xb = x3 + (size_t)b * DCH * LSP + (size_t)(dt_ * 32) * LSP + lt * 32;
  for (int i = threadIdx.x; i < 1024; i += 256) {
    int dd = i >> 5, ll = i & 31;
    tl[dd][ll] = xb[(size_t)dd * LSP + ll];
  }
  __syncthreads();
  for (int i = threadIdx.x; i < 1024; i += 256) {
    int ll = i >> 5, dd = i & 31;
    int n = b * 1024 + lt * 32 + ll;
    t16[(size_t)n * 384 + dt_ * 32 + dd] = f2bf(tl[dd][ll]);
  }
}

// ---------------- 3 weight arrays fp32 -> bf16, vectorized ----------------
__global__ void k_f2bf3(const float* __restrict__ s0, const float* __restrict__ s1,
                        const float* __restrict__ s2, unsigned short* __restrict__ d0,
                        unsigned short* __restrict__ d1, unsigned short* __restrict__ d2,
                        int n4) {
  int i = blockIdx.x * 256 + threadIdx.x;
  if (i >= n4) return;
  const float* s = (blockIdx.y == 0) ? s0 : (blockIdx.y == 1) ? s1 : s2;
  unsigned short* d = (blockIdx.y == 0) ? d0 : (blockIdx.y == 1) ? d1 : d2;
  float4 v = ((const float4*)s)[i];
  u16x4 o;
  o.x = f2bf(v.x); o.y = f2bf(v.y); o.z = f2bf(v.z); o.w = f2bf(v.w);
  ((u16x4*)d)[i] = o;
}

// ---- MoE GEMM1: he = silu(t@w1^T+b1)*(t@w3^T+b3); 64x128 tiles, flat expert tiles ----
__global__ void __launch_bounds__(256) k_moe1(
    const unsigned short* __restrict__ t16, const unsigned short* __restrict__ w1,
    const unsigned short* __restrict__ w3, const float* __restrict__ b1,
    const float* __restrict__ b3, const int* __restrict__ ltok,
    const int* __restrict__ cnt, const int* __restrict__ offs,
    const int* __restrict__ toff, unsigned short* __restrict__ he) {
  int tb = blockIdx.x;
  if (tb >= toff[8]) return;
  int e = 0;
  #pragma unroll
  for (int i = 1; i < 8; i++) if (toff[i] <= tb) e = i;
  int rt = tb - toff[e];
  int ne = cnt[e], base = offs[e];
  int ct = blockIdx.y;                  // 6 col tiles of 128 over HID
  __shared__ unsigned short As[64 * 40];
  __shared__ unsigned short B1s[128 * 40], B3s[128 * 40];
  __shared__ int toks[64];
  int tid = threadIdx.x;
  if (tid < 64) {
    int r = rt * 64 + tid;
    toks[tid] = ltok[base + (r < ne ? r : ne - 1)];
  }
  __syncthreads();
  int lane = tid & 63, wave = tid >> 6;
  int wm = (wave & 1) * 32, wn = (wave >> 1) * 64;
  int fm = lane & 15, fq = lane >> 4;
  f32x4 acc1[2][4], acc3[2][4];
  #pragma unroll
  for (int mi = 0; mi < 2; mi++)
    #pragma unroll
    for (int ni = 0; ni < 4; ni++) { acc1[mi][ni] = (f32x4)(0.f); acc3[mi][ni] = (f32x4)(0.f); }
  int lrow = tid >> 2, lkk = (tid & 3) * 8;
  const unsigned short* w1e = w1 + ((size_t)e * 768 + ct * 128) * 384;
  const unsigned short* w3e = w3 + ((size_t)e * 768 + ct * 128) * 384;
  size_t arow = (size_t)toks[lrow] * 384;
  for (int k0 = 0; k0 < 384; k0 += 32) {
    *(bf16x8*)&As[lrow * 40 + lkk]          = *(const bf16x8*)(t16 + arow + k0 + lkk);
    *(bf16x8*)&B1s[lrow * 40 + lkk]         = *(const bf16x8*)(w1e + (size_t)lrow * 384 + k0 + lkk);
    *(bf16x8*)&B1s[(lrow + 64) * 40 + lkk]  = *(const bf16x8*)(w1e + (size_t)(lrow + 64) * 384 + k0 + lkk);
    *(bf16x8*)&B3s[lrow * 40 + lkk]         = *(const bf16x8*)(w3e + (size_t)lrow * 384 + k0 + lkk);
    *(bf16x8*)&B3s[(lrow + 64) * 40 + lkk]  = *(const bf16x8*)(w3e + (size_t)(lrow + 64) * 384 + k0 + lkk);
    __syncthreads();
    bf16x8 av[2];
    #pragma unroll
    for (int mi = 0; mi < 2; mi++) av[mi] = *(bf16x8*)&As[(wm + mi * 16 + fm) * 40 + fq * 8];
    #pragma unroll
    for (int ni = 0; ni < 4; ni++) {
      bf16x8 b1v = *(bf16x8*)&B1s[(wn + ni * 16 + fm) * 40 + fq * 8];
      bf16x8 b3v = *(bf16x8*)&B3s[(wn + ni * 16 + fm) * 40 + fq * 8];
      #pragma unroll
      for (int mi = 0; mi < 2; mi++) {
        acc1[mi][ni] = __builtin_amdgcn_mfma_f32_16x16x32_bf16(av[mi], b1v, acc1[mi][ni], 0, 0, 0);
        acc3[mi][ni] = __builtin_amdgcn_mfma_f32_16x16x32_bf16(av[mi], b3v, acc3[mi][ni], 0, 0, 0);
      }
    }
    __syncthreads();
  }
  #pragma unroll
  for (int mi = 0; mi < 2; mi++)
    #pragma unroll
    for (int ni = 0; ni < 4; ni++)
      #pragma unroll
      for (int r = 0; r < 4; r++) {
        int lr = wm + mi * 16 + fq * 4 + r;
        int gr = rt * 64 + lr;
        if (gr < ne) {
          int col = ct * 128 + wn + ni * 16 + fm;
          float z1 = acc1[mi][ni][r] + b1[e * 768 + col];
          float z3 = acc3[mi][ni][r] + b3[e * 768 + col];
          float val = (z1 / (1.f + __expf(-z1))) * z3;
          he[((size_t)base + gr) * 768 + col] = f2bf(val);
        }
      }
}

// ---- MoE GEMM2: ymoe[pos][col] = (he@w2^T + b2) * lp, bf16, non-atomic ----
__global__ void __launch_bounds__(256) k_moe2(
    const unsigned short* __restrict__ he, const unsigned short* __restrict__ w2,
    const float* __restrict__ b2, const float* __restrict__ lp,
    const int* __restrict__ cnt, const int* __restrict__ offs,
    const int* __restrict__ toff, unsigned short* __restrict__ ymoe) {
  int tb = blockIdx.x;
  if (tb >= toff[8]) return;
  int e = 0;
  #pragma unroll
  for (int i = 1; i < 8; i++) if (toff[i] <= tb) e = i;
  int rt = tb - toff[e];
  int ne = cnt[e], base = offs[e];
  int ct = blockIdx.y;                  // 3 col tiles of 128 over D
  __shared__ unsigned short As[64 * 40];
  __shared__ unsigned short Bs[128 * 40];
  __shared__ float lps[64];
  int tid = threadIdx.x;
  if (tid < 64) {
    int r = rt * 64 + tid;
    lps[tid] = lp[base + (r < ne ? r : ne - 1)];
  }
  int lane = tid & 63, wave = tid >> 6;
  int wm = (wave & 1) * 32, wn = (wave >> 1) * 64;
  int fm = lane & 15, fq = lane >> 4;
  f32x4 acc[2][4];
  #pragma unroll
  for (int mi = 0; mi < 2; mi++)
    #pragma unroll
    for (int ni = 0; ni < 4; ni++) acc[mi][ni] = (f32x4)(0.f);
  int lrow = tid >> 2, lkk = (tid & 3) * 8;
  int ar = base + rt * 64 + lrow; if (ar > 32767) ar = 32767;
  const unsigned short* Arow = he + (size_t)ar * 768;
  const unsigned short* Brow = w2 + ((size_t)e * 384 + ct * 128 + lrow) * 768;
  const unsigned short* Brow2 = Brow + (size_t)64 * 768;
  for (int k0 = 0; k0 < 768; k0 += 32) {
    *(bf16x8*)&As[lrow * 40 + lkk]         = *(const bf16x8*)(Arow + k0 + lkk);
    *(bf16x8*)&Bs[lrow * 40 + lkk]         = *(const bf16x8*)(Brow + k0 + lkk);
    *(bf16x8*)&Bs[(lrow + 64) * 40 + lkk]  = *(const bf16x8*)(Brow2 + k0 + lkk);
    __syncthreads();
    bf16x8 av[2];
    #pragma unroll
    for (int mi = 0; mi < 2; mi++) av[mi] = *(bf16x8*)&As[(wm + mi * 16 + fm) * 40 + fq * 8];
    #pragma unroll
    for (int ni = 0; ni < 4; ni++) {
      bf16x8 bv = *(bf16x8*)&Bs[(wn + ni * 16 + fm) * 40 + fq * 8];
      #pragma unroll
      for (int mi = 0; mi < 2; mi++)
        acc[mi][ni] = __builtin_amdgcn_mfma_f32_16x16x32_bf16(av[mi], bv, acc[mi][ni], 0, 0, 0);
    }
    __syncthreads();
  }
  #pragma unroll
  for (int mi = 0; mi < 2; mi++)
    #pragma unroll
    for (int ni = 0; ni < 4; ni++)
      #pragma unroll
      for (int r = 0; r < 4; r++) {
        int lr = wm + mi * 16 + fq * 4 + r;
        int gr = rt * 64 + lr;
        if (gr < ne) {
          int col = ct * 128 + wn + ni * 16 + fm;
          float val = (acc[mi][ni][r] + b2[e * 384 + col]) * lps[lr];
          ymoe[((size_t)base + gr) * 384 + col] = f2bf(val);
        }
      }
}

// ---- gather each token's two ymoe rows, add into xout (transposed layout) ----
__global__ void k_scatter(const unsigned short* __restrict__ ymoe,
                          const int* __restrict__ tpos, float* __restrict__ xout) {
  int dt_ = blockIdx.x;  // 12 tiles of 32 d
  int lt = blockIdx.y;   // 16 tiles of 64 l
  int b = blockIdx.z;    // 16
  int l = threadIdx.x & 63;
  int d0 = dt_ * 32 + (threadIdx.x >> 6) * 8;
  int n = b * 1024 + lt * 64 + l;
  int p0 = tpos[2 * n], p1 = tpos[2 * n + 1];
  bf16x8 y0 = *(const bf16x8*)(ymoe + (size_t)p0 * 384 + d0);
  bf16x8 y1 = *(const bf16x8*)(ymoe + (size_t)p1 * 384 + d0);
  size_t base = (size_t)b * DCH * LSP + (size_t)d0 * LSP + lt * 64 + l;
  #pragma unroll
  for (int k = 0; k < 8; k++) {
    float v = bf2f((unsigned short)y0[k]) + bf2f((unsigned short)y1[k]);
    xout[base + (size_t)k * LSP] += v;
  }
}

extern "C" void kernel_launch(void* const* d_in, const int* in_sizes, int n_in,
                              void* d_out, int out_size, void* d_ws, size_t ws_size,
                              hipStream_t stream) {
  const float* x      = (const float*)d_in[0];
  const float* dw1    = (const float*)d_in[1];
  const float* bn1g   = (const float*)d_in[2];
  const float* bn1b   = (const float*)d_in[3];
  const float* bn1m   = (const float*)d_in[4];
  const float* bn1v   = (const float*)d_in[5];
  const float* dw2    = (const float*)d_in[6];
  const float* bn2g   = (const float*)d_in[7];
  const float* bn2b   = (const float*)d_in[8];
  const float* bn2m   = (const float*)d_in[9];
  const float* bn2v   = (const float*)d_in[10];
  const float* lnw    = (const float*)d_in[11];
  const float* lnb    = (const float*)d_in[12];
  const float* bcdtw  = (const float*)d_in[13];
  const float* dwsw   = (const float*)d_in[14];
  const float* hprojw = (const float*)d_in[15];
  const float* Avec   = (const float*)d_in[16];
  const float* gatew  = (const float*)d_in[17];
  const float* gateb  = (const float*)d_in[18];
  const float* w1f    = (const float*)d_in[19];
  const float* b1f    = (const float*)d_in[20];
  const float* w2f    = (const float*)d_in[21];
  const float* b2f    = (const float*)d_in[22];
  const float* w3f    = (const float*)d_in[23];
  const float* b3f    = (const float*)d_in[24];

  char* wsb = (char*)d_ws;
  float* x1    = (float*)(wsb + OFF_X1);
  float* xn    = (float*)(wsb + OFF_XN);
  float* bcdt  = (float*)(wsb + OFF_BCDT);
  float* bcdtc = (float*)(wsb + OFF_BCDTC);
  float* hbuf  = (float*)(wsb + OFF_H);
  float* x2    = (float*)(wsb + OFF_X2);
  float* logits = (float*)(wsb + OFF_LOGITS);
  float* probs  = (float*)(wsb + OFF_PROBS);
  int*   idx    = (int*)(wsb + OFF_IDX);
  int*   cnt    = (int*)(wsb + OFF_CNT);
  int*   fill   = (int*)(wsb + OFF_FILL);
  int*   offs   = (int*)(wsb + OFF_OFFS);
  int*   toff   = (int*)(wsb + OFF_TOFF);
  int*   ltok   = (int*)(wsb + OFF_LTOK);
  float* lp     = (float*)(wsb + OFF_LP);
  int*   tpos   = (int*)(wsb + OFF_TPOS);
  unsigned short* t16  = (unsigned short*)(wsb + OFF_T16);
  unsigned short* w1b  = (unsigned short*)(wsb + OFF_W1B);
  unsigned short* w3b  = (unsigned short*)(wsb + OFF_W3B);
  unsigned short* w2b  = (unsigned short*)(wsb + OFF_W2B);
  unsigned short* he   = (unsigned short*)(wsb + OFF_HE);
  unsigned short* ymoe = (unsigned short*)(wsb + OFF_YMOE);
  float* xout = (float*)d_out;
  float* h2   = xout + (size_t)BSZ * DCH * LSP;   // second output region

  // stage 1: x1 = x + bn1(dw1(x))
  k_dwbnres<<<BSZ * DCH, 256, 0, stream>>>(x, dw1, bn1g, bn1b, bn1m, bn1v, x1, DCH);
  // stage 2: layernorm -> xn
  k_layernorm<<<NTOK / 64, 256, 0, stream>>>(x1, lnw, lnb, xn);
  // stage 3: bcdt = bcdt_w @ xn
  k_bcdt<<<dim3(8, 3, BSZ), 256, 0, stream>>>(xn, bcdtw, bcdt);
  // stage 4: depthwise conv on bcdt
  k_dwbnres<<<BSZ * 192, 256, 0, stream>>>(bcdt, dwsw, nullptr, nullptr, nullptr, nullptr, bcdtc, 192);
  // stage 5: softmax(dt + A) over L
  k_softmax<<<BSZ * SST, 256, 0, stream>>>(bcdtc, Avec);
  // stage 6: h = xn @ (Am*Bm)^T
  k_h<<<dim3(6, BSZ), 256, 0, stream>>>(xn, bcdtc, hbuf);
  // stage 7: h2 = silu(hproj @ h)  (second output)
  k_hproj<<<dim3(6, BSZ), 256, 0, stream>>>(hbuf, hprojw, h2);
  // stage 8: x2 = x1 + h2 @ Cm
  k_y<<<dim3(8, 12, BSZ), 256, 0, stream>>>(h2, bcdtc, x1, x2);
  // stage 9: x3 = x2 + bn2(dw2(x2)) -> d_out
  k_dwbnres<<<BSZ * DCH, 256, 0, stream>>>(x2, dw2, bn2g, bn2b, bn2m, bn2v, xout, DCH);
  // MoE routing
  hipMemsetAsync(wsb + OFF_CNT, 0, 64, stream);   // cnt + fill
  k_router<<<256, 256, 0, stream>>>(xout, gatew, gateb, logits);
  k_topk<<<NTOK / 256, 256, 0, stream>>>(logits, probs, idx, cnt);
  k_offsets<<<1, 64, 0, stream>>>(cnt, offs, toff);
  k_build<<<NTOK / 256, 256, 0, stream>>>(idx, probs, offs, fill, ltok, lp, tpos);
  // tokens + weights to bf16
  k_t16<<<dim3(32, 12, BSZ), 256, 0, stream>>>(xout, t16);
  int n4 = NEXP * HID * DCH / 4;
  k_f2bf3<<<dim3((n4 + 255) / 256, 3), 256, 0, stream>>>(w1f, w3f, w2f, w1b, w3b, w2b, n4);
  // MoE GEMMs: single launch each, flat (expert,row-tile) index
  k_moe1<<<dim3(MOE_MAXT, 6), 256, 0, stream>>>(t16, w1b, w3b, b1f, b3f, ltok, cnt, offs, toff, he);
  k_moe2<<<dim3(MOE_MAXT, 3), 256, 0, stream>>>(he, w2b, b2f, lp, cnt, offs, toff, ymoe);
  // gather + residual add
  k_scatter<<<dim3(12, 16, BSZ), 256, 0, stream>>>(ymoe, tpos, xout);
}

// Round 3
// 586.660 us; speedup vs baseline: 2.9821x; 1.1749x over previous
//
#include <hip/hip_runtime.h>
#include <hip/hip_bf16.h>

#define BSZ 16
#define DCH 384
#define LSP 1024
#define SST 64
#define NEXP 8
#define HID 768
#define NTOK 16384   // BSZ*LSP
#define MOE_MAXT 520 // max row tiles of 64 across experts: 32768/64 + 8

// ---- workspace byte offsets (exact-fit overlays, lifetimes checked) ----
#define OFF_X1    0ULL            // 25165824  (dead after k_y)
#define OFF_XN    25165824ULL     // 25165824  (dead after k_h)
#define OFF_BCDT  50331648ULL     // 12582912  (dead after dws conv)
#define OFF_BCDTC 62914560ULL     // 12582912  (Bm/Cm/Am; dead after k_y)
#define OFF_H     75497472ULL     // 1572864   (dead after k_hproj)
#define OFF_X2    77070336ULL     // 25165824  (dead after dwconv2)
#define OFF_META  102236160ULL    // ~1.2 MB used
#define OFF_LOGITS (OFF_META)                  // 524288
#define OFF_PROBS  (OFF_META +  524288ULL)     // 131072
#define OFF_IDX    (OFF_META +  655360ULL)     // 131072
#define OFF_CNT    (OFF_META +  786432ULL)     // 32
#define OFF_FILL   (OFF_META +  786464ULL)     // 32
#define OFF_OFFS   (OFF_META +  786496ULL)     // 32
#define OFF_TOFF   (OFF_META +  786560ULL)     // 64 (tile prefix, 9 ints)
#define OFF_LTOK   (OFF_META +  786624ULL)     // 131072
#define OFF_LP     (OFF_META +  917696ULL)     // 131072
#define OFF_TPOS   (OFF_META + 1048768ULL)     // 131072 -> ends 1179840
// overlays (used only after their hosts are dead):
#define OFF_HE    0ULL                      // 32768*768*2 = 50331648 == x1+xn
#define OFF_T16   OFF_BCDT                  // 16384*384*2 = 12582912 exact
#define OFF_W1B   OFF_BCDTC                 // 4718592
#define OFF_W3B   (OFF_BCDTC + 4718592ULL)
#define OFF_W2B   (OFF_BCDTC + 9437184ULL)  // ends exactly at OFF_X2
#define OFF_YMOE  OFF_X2                    // 32768*384*2 = 25165824 == x2 exactly
#define OFF_HPRE  OFF_X2                    // 1572864; dead before k_y writes x2

typedef __attribute__((ext_vector_type(8))) short bf16x8;
typedef __attribute__((ext_vector_type(4))) float f32x4;
typedef __attribute__((ext_vector_type(4))) unsigned short u16x4;

__device__ __forceinline__ unsigned short f2bf(float f) {
  union { float f; unsigned int u; } x; x.f = f;
  unsigned int r = (x.u + 0x7fffu + ((x.u >> 16) & 1u)) >> 16;  // RNE
  return (unsigned short)r;
}
__device__ __forceinline__ float bf2f(unsigned short s) {
  union { unsigned int u; float f; } x; x.u = ((unsigned int)s) << 16; return x.f;
}

// ---------------- depthwise 3x3 (+ optional BN + residual) ----------------
__global__ void k_dwbnres(const float* __restrict__ x, const float* __restrict__ w,
                          const float* __restrict__ g, const float* __restrict__ bb,
                          const float* __restrict__ mm, const float* __restrict__ vv,
                          float* __restrict__ out, int C) {
  int bc = blockIdx.x;
  int c = bc % C;
  __shared__ float tile[34 * 34];
  const float* img = x + (size_t)bc * 1024;
  for (int i = threadIdx.x; i < 34 * 34; i += 256) tile[i] = 0.f;
  __syncthreads();
  for (int i = threadIdx.x; i < 1024; i += 256) {
    int r = i >> 5, cc = i & 31;
    tile[(r + 1) * 34 + (cc + 1)] = img[i];
  }
  __syncthreads();
  float w0 = w[c*9+0], w1 = w[c*9+1], w2 = w[c*9+2], w3 = w[c*9+3], w4 = w[c*9+4],
        w5 = w[c*9+5], w6 = w[c*9+6], w7 = w[c*9+7], w8 = w[c*9+8];
  bool res = (g != nullptr);
  float scale = 1.f, bias = 0.f;
  if (res) { float s = g[c] * rsqrtf(vv[c] + 1e-5f); scale = s; bias = bb[c] - mm[c] * s; }
  for (int i = threadIdx.x; i < 1024; i += 256) {
    int r = i >> 5, cc = i & 31;
    const float* t0 = &tile[r * 34 + cc];
    float acc = t0[0]*w0 + t0[1]*w1 + t0[2]*w2
              + t0[34]*w3 + t0[35]*w4 + t0[36]*w5
              + t0[68]*w6 + t0[69]*w7 + t0[70]*w8;
    float o = res ? (t0[35] + acc * scale + bias) : acc;
    out[(size_t)bc * 1024 + i] = o;
  }
}

// ---------------- LayerNorm over channel dim of (B, D, L) ----------------
__global__ void k_layernorm(const float* __restrict__ x, const float* __restrict__ lw,
                            const float* __restrict__ lb, float* __restrict__ xn) {
  int lane = threadIdx.x & 63;
  int slice = threadIdx.x >> 6;           // 4 slices of 96 channels
  int pos0 = blockIdx.x * 64;             // 64 positions, all same b
  int b = pos0 >> 10;
  int l = (pos0 & 1023) + lane;
  const float* xb = x + (size_t)b * DCH * LSP + l;
  float s = 0.f, s2 = 0.f;
  for (int d = slice * 96; d < slice * 96 + 96; d++) {
    float v = xb[(size_t)d * LSP];
    s += v; s2 += v * v;
  }
  __shared__ float red[2][4][64];
  red[0][slice][lane] = s; red[1][slice][lane] = s2;
  __syncthreads();
  if (slice == 0) {
    s  = red[0][0][lane] + red[0][1][lane] + red[0][2][lane] + red[0][3][lane];
    s2 = red[1][0][lane] + red[1][1][lane] + red[1][2][lane] + red[1][3][lane];
    float mu = s * (1.f / 384.f);
    float var = s2 * (1.f / 384.f) - mu * mu;
    red[0][0][lane] = mu;
    red[1][0][lane] = rsqrtf(var + 1e-5f);
  }
  __syncthreads();
  float mu = red[0][0][lane], rs = red[1][0][lane];
  float* xnb = xn + (size_t)b * DCH * LSP + l;
  for (int d = slice * 96; d < slice * 96 + 96; d++) {
    float v = xb[(size_t)d * LSP];
    xnb[(size_t)d * LSP] = (v - mu) * rs * lw[d] + lb[d];
  }
}

// ---------------- bcdt = bcdt_w(192x384) @ xn(b,384,1024) ----------------
__global__ void k_bcdt(const float* __restrict__ xn, const float* __restrict__ wt,
                       float* __restrict__ out) {
  int lt = blockIdx.x, ct = blockIdx.y, b = blockIdx.z;   // (8, 3, 16)
  __shared__ float wsm[64][33];
  __shared__ float xs[32][129];
  int lg = threadIdx.x & 31, cg = threadIdx.x >> 5;
  float acc[8][4];
  for (int i = 0; i < 8; i++) for (int j = 0; j < 4; j++) acc[i][j] = 0.f;
  const float* xb = xn + (size_t)b * DCH * LSP + lt * 128;
  for (int d0 = 0; d0 < 384; d0 += 32) {
    for (int i = threadIdx.x; i < 2048; i += 256) {
      int c = i >> 5, dd = i & 31;
      wsm[c][dd] = wt[(size_t)(ct * 64 + c) * 384 + d0 + dd];
    }
    for (int i = threadIdx.x; i < 4096; i += 256) {
      int dd = i >> 7, ll = i & 127;
      xs[dd][ll] = xb[(size_t)(d0 + dd) * LSP + ll];
    }
    __syncthreads();
    for (int dd = 0; dd < 32; dd++) {
      float xv[4];
      #pragma unroll
      for (int il = 0; il < 4; il++) xv[il] = xs[dd][lg + 32 * il];
      #pragma unroll
      for (int ic = 0; ic < 8; ic++) {
        float wv = wsm[cg + 8 * ic][dd];
        #pragma unroll
        for (int il = 0; il < 4; il++) acc[ic][il] += wv * xv[il];
      }
    }
    __syncthreads();
  }
  for (int ic = 0; ic < 8; ic++)
    for (int il = 0; il < 4; il++)
      out[(size_t)b * 196608 + (size_t)(ct * 64 + cg + 8 * ic) * 1024 + lt * 128 + lg + 32 * il] = acc[ic][il];
}

// ---------------- softmax over L on dt rows (in place) ----------------
__global__ void k_softmax(float* __restrict__ bc, const float* __restrict__ Av) {
  int b = blockIdx.x >> 6, s = blockIdx.x & 63;
  float* row = bc + (size_t)b * 196608 + (size_t)(128 + s) * 1024;
  float a = Av[s];
  int t = threadIdx.x;
  float v[4]; float mx = -3.0e38f;
  #pragma unroll
  for (int i = 0; i < 4; i++) { v[i] = row[t + 256 * i] + a; mx = fmaxf(mx, v[i]); }
  #pragma unroll
  for (int off = 32; off >= 1; off >>= 1) mx = fmaxf(mx, __shfl_xor(mx, off));
  __shared__ float redm[4], reds[4];
  if ((t & 63) == 0) redm[t >> 6] = mx;
  __syncthreads();
  mx = fmaxf(fmaxf(redm[0], redm[1]), fmaxf(redm[2], redm[3]));
  float sm = 0.f;
  #pragma unroll
  for (int i = 0; i < 4; i++) { v[i] = __expf(v[i] - mx); sm += v[i]; }
  #pragma unroll
  for (int off = 32; off >= 1; off >>= 1) sm += __shfl_xor(sm, off);
  if ((t & 63) == 0) reds[t >> 6] = sm;
  __syncthreads();
  sm = reds[0] + reds[1] + reds[2] + reds[3];
  float inv = 1.f / sm;
  #pragma unroll
  for (int i = 0; i < 4; i++) row[t + 256 * i] = v[i] * inv;
}

// ---- h[b,d,s] += sum_{l in chunk} xn[b,d,l] * (Am*Bm)[b,s,l]; L split 8-way ----
__global__ void k_h(const float* __restrict__ xn, const float* __restrict__ bc,
                    float* __restrict__ h) {
  int dt_ = blockIdx.x, ls = blockIdx.y, b = blockIdx.z;   // (6, 8, 16)
  __shared__ float xs[64][65];
  __shared__ float ab[64][65];
  int tid = threadIdx.x;
  int sg4 = tid & 15, dg4 = tid >> 4;     // 16x16 thread grid, 4x4 regs each
  float acc[4][4];
  #pragma unroll
  for (int i = 0; i < 4; i++)
    #pragma unroll
    for (int j = 0; j < 4; j++) acc[i][j] = 0.f;
  const float* Bm = bc + (size_t)b * 196608;
  const float* Am = Bm + 131072;
  const float* xb = xn + (size_t)b * DCH * LSP + (size_t)(dt_ * 64) * LSP;
  for (int l0 = ls * 128; l0 < ls * 128 + 128; l0 += 64) {
    for (int i = tid; i < 4096; i += 256) {
      int r = i >> 6, ll = i & 63;
      xs[r][ll] = xb[(size_t)r * LSP + l0 + ll];
      ab[r][ll] = Am[(size_t)r * 1024 + l0 + ll] * Bm[(size_t)r * 1024 + l0 + ll];
    }
    __syncthreads();
    for (int ll = 0; ll < 64; ll++) {
      float xv[4], av[4];
      #pragma unroll
      for (int i = 0; i < 4; i++) xv[i] = xs[dg4 * 4 + i][ll];
      #pragma unroll
      for (int j = 0; j < 4; j++) av[j] = ab[sg4 * 4 + j][ll];
      #pragma unroll
      for (int i = 0; i < 4; i++)
        #pragma unroll
        for (int j = 0; j < 4; j++) acc[i][j] += xv[i] * av[j];
    }
    __syncthreads();
  }
  float* hb = h + (size_t)b * DCH * SST + (size_t)(dt_ * 64) * 64;
  #pragma unroll
  for (int i = 0; i < 4; i++)
    #pragma unroll
    for (int j = 0; j < 4; j++)
      atomicAdd(&hb[(size_t)(dg4 * 4 + i) * 64 + sg4 * 4 + j], acc[i][j]);
}

// ---- hpre[b,e,s] += sum_{d in chunk} pw[e,d]*h[b,d,s]; K split 3-way ----
__global__ void k_hproj(const float* __restrict__ h, const float* __restrict__ pw,
                        float* __restrict__ hpre) {
  int et = blockIdx.x, ks = blockIdx.y, b = blockIdx.z;   // (6, 3, 16)
  __shared__ float hs[64][65];   // [d][s]
  __shared__ float ps[64][65];   // [e][d]
  int tid = threadIdx.x;
  int sg4 = tid & 15, eg4 = tid >> 4;
  float acc[4][4];
  #pragma unroll
  for (int i = 0; i < 4; i++)
    #pragma unroll
    for (int j = 0; j < 4; j++) acc[i][j] = 0.f;
  for (int d0 = ks * 128; d0 < ks * 128 + 128; d0 += 64) {
    for (int i = tid; i < 4096; i += 256) {
      int r = i >> 6, cc = i & 63;
      hs[r][cc] = h[(size_t)b * DCH * SST + (size_t)(d0 + r) * 64 + cc];
      ps[r][cc] = pw[(size_t)(et * 64 + r) * 384 + d0 + cc];
    }
    __syncthreads();
    for (int dd = 0; dd < 64; dd++) {
      float pv[4], hv[4];
      #pragma unroll
      for (int i = 0; i < 4; i++) pv[i] = ps[eg4 * 4 + i][dd];
      #pragma unroll
      for (int j = 0; j < 4; j++) hv[j] = hs[dd][sg4 * 4 + j];
      #pragma unroll
      for (int i = 0; i < 4; i++)
        #pragma unroll
        for (int j = 0; j < 4; j++) acc[i][j] += pv[i] * hv[j];
    }
    __syncthreads();
  }
  float* hb = hpre + (size_t)b * DCH * SST + (size_t)(et * 64) * 64;
  #pragma unroll
  for (int i = 0; i < 4; i++)
    #pragma unroll
    for (int j = 0; j < 4; j++)
      atomicAdd(&hb[(size_t)(eg4 * 4 + i) * 64 + sg4 * 4 + j], acc[i][j]);
}

// ---- h2 = silu(hpre), vectorized ----
__global__ void k_silu(const float* __restrict__ hpre, float* __restrict__ h2) {
  int i = blockIdx.x * 256 + threadIdx.x;   // over 98304 float4s
  float4 v = ((const float4*)hpre)[i];
  v.x = v.x / (1.f + __expf(-v.x));
  v.y = v.y / (1.f + __expf(-v.y));
  v.z = v.z / (1.f + __expf(-v.z));
  v.w = v.w / (1.f + __expf(-v.w));
  ((float4*)h2)[i] = v;
}

// ---------------- x2 = x1 + h2 @ Cm ----------------
__global__ void k_y(const float* __restrict__ h2, const float* __restrict__ bc,
                    const float* __restrict__ x1, float* __restrict__ x2) {
  int lt = blockIdx.x, dt_ = blockIdx.y, b = blockIdx.z;   // (8, 12, 16)
  __shared__ float hss[32][65];
  __shared__ float cs[64][129];
  int lg = threadIdx.x & 31, dg = threadIdx.x >> 5;
  float acc[4][4];
  for (int i = 0; i < 4; i++) for (int j = 0; j < 4; j++) acc[i][j] = 0.f;
  for (int i = threadIdx.x; i < 2048; i += 256) {
    int r = i >> 6, cc = i & 63;
    hss[r][cc] = h2[(size_t)b * DCH * SST + (size_t)(dt_ * 32 + r) * 64 + cc];
  }
  const float* Cm = bc + (size_t)b * 196608 + 65536;
  for (int i = threadIdx.x; i < 8192; i += 256) {
    int ss = i >> 7, ll = i & 127;
    cs[ss][ll] = Cm[(size_t)ss * 1024 + lt * 128 + ll];
  }
  __syncthreads();
  for (int ss = 0; ss < 64; ss++) {
    float cv[4];
    #pragma unroll
    for (int il = 0; il < 4; il++) cv[il] = cs[ss][lg + 32 * il];
    #pragma unroll
    for (int id = 0; id < 4; id++) {
      float hv = hss[dg * 4 + id][ss];
      #pragma unroll
      for (int il = 0; il < 4; il++) acc[id][il] += hv * cv[il];
    }
  }
  size_t base = (size_t)b * DCH * LSP + (size_t)(dt_ * 32) * LSP + lt * 128;
  for (int id = 0; id < 4; id++)
    for (int il = 0; il < 4; il++) {
      size_t o = base + (size_t)(dg * 4 + id) * LSP + lg + 32 * il;
      x2[o] = x1[o] + acc[id][il];
    }
}

// ---------------- router logits ----------------
__global__ void k_router(const float* __restrict__ x3, const float* __restrict__ gw,
                         const float* __restrict__ gb, float* __restrict__ logits) {
  __shared__ float xs[64][65];
  __shared__ float gs[8][64];
  int blk = blockIdx.x;                  // 256 blocks of 64 tokens
  int b = blk >> 4; int l0 = (blk & 15) * 64;
  int lg = threadIdx.x & 63, eg = threadIdx.x >> 6;
  float acc0 = 0.f, acc1 = 0.f;
  const float* xb = x3 + (size_t)b * DCH * LSP + l0;
  for (int d0 = 0; d0 < 384; d0 += 64) {
    for (int i = threadIdx.x; i < 4096; i += 256) {
      int dd = i >> 6, ll = i & 63;
      xs[dd][ll] = xb[(size_t)(d0 + dd) * LSP + ll];
    }
    for (int i = threadIdx.x; i < 512; i += 256) {
      int e = i >> 6, dd = i & 63;
      gs[e][dd] = gw[(size_t)e * 384 + d0 + dd];
    }
    __syncthreads();
    for (int dd = 0; dd < 64; dd++) {
      float xv = xs[dd][lg];
      acc0 += gs[eg][dd] * xv;
      acc1 += gs[eg + 4][dd] * xv;
    }
    __syncthreads();
  }
  int n = b * 1024 + l0 + lg;
  logits[(size_t)n * 8 + eg]     = acc0 + gb[eg];
  logits[(size_t)n * 8 + eg + 4] = acc1 + gb[eg + 4];
}

// ---------------- top-2 + softmax + counts (LDS-aggregated atomics) ----------------
__global__ void k_topk(const float* __restrict__ logits, float* __restrict__ probs,
                       int* __restrict__ idx, int* __restrict__ cnt) {
  __shared__ int lcnt[8];
  if (threadIdx.x < 8) lcnt[threadIdx.x] = 0;
  __syncthreads();
  int n = blockIdx.x * 256 + threadIdx.x;
  float lv[8];
  for (int e = 0; e < 8; e++) lv[e] = logits[(size_t)n * 8 + e];
  int i1 = 0; float v1 = lv[0];
  for (int e = 1; e < 8; e++) if (lv[e] > v1) { v1 = lv[e]; i1 = e; }
  int i2 = -1; float v2 = -3.0e38f;
  for (int e = 0; e < 8; e++) { if (e == i1) continue; if (lv[e] > v2) { v2 = lv[e]; i2 = e; } }
  float p1 = 1.f / (1.f + __expf(v2 - v1));
  probs[n * 2] = p1; probs[n * 2 + 1] = 1.f - p1;
  idx[n * 2] = i1; idx[n * 2 + 1] = i2;
  atomicAdd(&lcnt[i1], 1); atomicAdd(&lcnt[i2], 1);
  __syncthreads();
  if (threadIdx.x < 8) atomicAdd(&cnt[threadIdx.x], lcnt[threadIdx.x]);
}

__global__ void k_offsets(const int* __restrict__ cnt, int* __restrict__ offs,
                          int* __restrict__ toff) {
  if (threadIdx.x == 0) {
    int a = 0, t = 0;
    for (int e = 0; e < 8; e++) {
      offs[e] = a; toff[e] = t;
      a += cnt[e]; t += (cnt[e] + 63) >> 6;
    }
    toff[8] = t;
  }
}

// ---------------- build expert token lists (LDS-aggregated) ----------------
__global__ void k_build(const int* __restrict__ idx, const float* __restrict__ probs,
                        const int* __restrict__ offs, int* __restrict__ fill,
                        int* __restrict__ ltok, float* __restrict__ lp,
                        int* __restrict__ tpos) {
  __shared__ int lcnt[8], lbase[8];
  if (threadIdx.x < 8) lcnt[threadIdx.x] = 0;
  __syncthreads();
  int n = blockIdx.x * 256 + threadIdx.x;
  int e0 = idx[n * 2], e1 = idx[n * 2 + 1];
  int o0 = atomicAdd(&lcnt[e0], 1);
  int o1 = atomicAdd(&lcnt[e1], 1);
  __syncthreads();
  if (threadIdx.x < 8) lbase[threadIdx.x] = atomicAdd(&fill[threadIdx.x], lcnt[threadIdx.x]);
  __syncthreads();
  int p0 = offs[e0] + lbase[e0] + o0;
  int p1 = offs[e1] + lbase[e1] + o1;
  ltok[p0] = n; lp[p0] = probs[n * 2];     tpos[n * 2] = p0;
  ltok[p1] = n; lp[p1] = probs[n * 2 + 1]; tpos[n * 2 + 1] = p1;
}

// ---------------- tokens -> bf16 [N][D] (transpose) ----------------
__global__ void k_t16(const float* __restrict__ x3, unsigned short* __restrict__ t16) {
  __shared__ float tl[32][33];
  int lt = blockIdx.x, dt_ = blockIdx.y, b = blockIdx.z;   // (32, 12, 16)
  const float* xb = x3 + (size_t)b * DCH * LSP + (size_t)(dt_ * 32) * LSP + lt * 32;
  for (int i = threadIdx.x; i < 1024; i += 256) {
    int dd = i >> 5, ll = i & 31;
    tl[dd][ll] = xb[(size_t)dd * LSP + ll];
  }
  __syncthreads();
  for (int i = threadIdx.x; i < 1024; i += 256) {
    int ll = i >> 5, dd = i & 31;
    int n = b * 1024 + lt * 32 + ll;
    t16[(size_t)n * 384 + dt_ * 32 + dd] = f2bf(tl[dd][ll]);
  }
}

// ---------------- 3 weight arrays fp32 -> bf16, vectorized ----------------
__global__ void k_f2bf3(const float* __restrict__ s0, const float* __restrict__ s1,
                        const float* __restrict__ s2, unsigned short* __restrict__ d0,
                        unsigned short* __restrict__ d1, unsigned short* __restrict__ d2,
                        int n4) {
  int i = blockIdx.x * 256 + threadIdx.x;
  if (i >= n4) return;
  const float* s = (blockIdx.y == 0) ? s0 : (blockIdx.y == 1) ? s1 : s2;
  unsigned short* d = (blockIdx.y == 0) ? d0 : (blockIdx.y == 1) ? d1 : d2;
  float4 v = ((const float4*)s)[i];
  u16x4 o;
  o.x = f2bf(v.x); o.y = f2bf(v.y); o.z = f2bf(v.z); o.w = f2bf(v.w);
  ((u16x4*)d)[i] = o;
}

// ---- MoE GEMM1: he = silu(t@w1^T+b1)*(t@w3^T+b3); 64x128 tiles, flat expert tiles ----
__global__ void __launch_bounds__(256) k_moe1(
    const unsigned short* __restrict__ t16, const unsigned short* __restrict__ w1,
    const unsigned short* __restrict__ w3, const float* __restrict__ b1,
    const float* __restrict__ b3, const int* __restrict__ ltok,
    const int* __restrict__ cnt, const int* __restrict__ offs,
    const int* __restrict__ toff, unsigned short* __restrict__ he) {
  int tb = blockIdx.x;
  if (tb >= toff[8]) return;
  int e = 0;
  #pragma unroll
  for (int i = 1; i < 8; i++) if (toff[i] <= tb) e = i;
  int rt = tb - toff[e];
  int ne = cnt[e], base = offs[e];
  int ct = blockIdx.y;                  // 6 col tiles of 128 over HID
  __shared__ unsigned short As[64 * 40];
  __shared__ unsigned short B1s[128 * 40], B3s[128 * 40];
  __shared__ int toks[64];
  int tid = threadIdx.x;
  if (tid < 64) {
    int r = rt * 64 + tid;
    toks[tid] = ltok[base + (r < ne ? r : ne - 1)];
  }
  __syncthreads();
  int lane = tid & 63, wave = tid >> 6;
  int wm = (wave & 1) * 32, wn = (wave >> 1) * 64;
  int fm = lane & 15, fq = lane >> 4;
  f32x4 acc1[2][4], acc3[2][4];
  #pragma unroll
  for (int mi = 0; mi < 2; mi++)
    #pragma unroll
    for (int ni = 0; ni < 4; ni++) { acc1[mi][ni] = (f32x4)(0.f); acc3[mi][ni] = (f32x4)(0.f); }
  int lrow = tid >> 2, lkk = (tid & 3) * 8;
  const unsigned short* w1e = w1 + ((size_t)e * 768 + ct * 128) * 384;
  const unsigned short* w3e = w3 + ((size_t)e * 768 + ct * 128) * 384;
  size_t arow = (size_t)toks[lrow] * 384;
  for (int k0 = 0; k0 < 384; k0 += 32) {
    *(bf16x8*)&As[lrow * 40 + lkk]          = *(const bf16x8*)(t16 + arow + k0 + lkk);
    *(bf16x8*)&B1s[lrow * 40 + lkk]         = *(const bf16x8*)(w1e + (size_t)lrow * 384 + k0 + lkk);
    *(bf16x8*)&B1s[(lrow + 64) * 40 + lkk]  = *(const bf16x8*)(w1e + (size_t)(lrow + 64) * 384 + k0 + lkk);
    *(bf16x8*)&B3s[lrow * 40 + lkk]         = *(const bf16x8*)(w3e + (size_t)lrow * 384 + k0 + lkk);
    *(bf16x8*)&B3s[(lrow + 64) * 40 + lkk]  = *(const bf16x8*)(w3e + (size_t)(lrow + 64) * 384 + k0 + lkk);
    __syncthreads();
    bf16x8 av[2];
    #pragma unroll
    for (int mi = 0; mi < 2; mi++) av[mi] = *(bf16x8*)&As[(wm + mi * 16 + fm) * 40 + fq * 8];
    #pragma unroll
    for (int ni = 0; ni < 4; ni++) {
      bf16x8 b1v = *(bf16x8*)&B1s[(wn + ni * 16 + fm) * 40 + fq * 8];
      bf16x8 b3v = *(bf16x8*)&B3s[(wn + ni * 16 + fm) * 40 + fq * 8];
      #pragma unroll
      for (int mi = 0; mi < 2; mi++) {
        acc1[mi][ni] = __builtin_amdgcn_mfma_f32_16x16x32_bf16(av[mi], b1v, acc1[mi][ni], 0, 0, 0);
        acc3[mi][ni] = __builtin_amdgcn_mfma_f32_16x16x32_bf16(av[mi], b3v, acc3[mi][ni], 0, 0, 0);
      }
    }
    __syncthreads();
  }
  #pragma unroll
  for (int mi = 0; mi < 2; mi++)
    #pragma unroll
    for (int ni = 0; ni < 4; ni++)
      #pragma unroll
      for (int r = 0; r < 4; r++) {
        int lr = wm + mi * 16 + fq * 4 + r;
        int gr = rt * 64 + lr;
        if (gr < ne) {
          int col = ct * 128 + wn + ni * 16 + fm;
          float z1 = acc1[mi][ni][r] + b1[e * 768 + col];
          float z3 = acc3[mi][ni][r] + b3[e * 768 + col];
          float val = (z1 / (1.f + __expf(-z1))) * z3;
          he[((size_t)base + gr) * 768 + col] = f2bf(val);
        }
      }
}

// ---- MoE GEMM2: ymoe[pos][col] = (he@w2^T + b2) * lp, bf16, non-atomic ----
__global__ void __launch_bounds__(256) k_moe2(
    const unsigned short* __restrict__ he, const unsigned short* __restrict__ w2,
    const float* __restrict__ b2, const float* __restrict__ lp,
    const int* __restrict__ cnt, const int* __restrict__ offs,
    const int* __restrict__ toff, unsigned short* __restrict__ ymoe) {
  int tb = blockIdx.x;
  if (tb >= toff[8]) return;
  int e = 0;
  #pragma unroll
  for (int i = 1; i < 8; i++) if (toff[i] <= tb) e = i;
  int rt = tb - toff[e];
  int ne = cnt[e], base = offs[e];
  int ct = blockIdx.y;                  // 3 col tiles of 128 over D
  __shared__ unsigned short As[64 * 40];
  __shared__ unsigned short Bs[128 * 40];
  __shared__ float lps[64];
  int tid = threadIdx.x;
  if (tid < 64) {
    int r = rt * 64 + tid;
    lps[tid] = lp[base + (r < ne ? r : ne - 1)];
  }
  int lane = tid & 63, wave = tid >> 6;
  int wm = (wave & 1) * 32, wn = (wave >> 1) * 64;
  int fm = lane & 15, fq = lane >> 4;
  f32x4 acc[2][4];
  #pragma unroll
  for (int mi = 0; mi < 2; mi++)
    #pragma unroll
    for (int ni = 0; ni < 4; ni++) acc[mi][ni] = (f32x4)(0.f);
  int lrow = tid >> 2, lkk = (tid & 3) * 8;
  int ar = base + rt * 64 + lrow; if (ar > 32767) ar = 32767;
  const unsigned short* Arow = he + (size_t)ar * 768;
  const unsigned short* Brow = w2 + ((size_t)e * 384 + ct * 128 + lrow) * 768;
  const unsigned short* Brow2 = Brow + (size_t)64 * 768;
  for (int k0 = 0; k0 < 768; k0 += 32) {
    *(bf16x8*)&As[lrow * 40 + lkk]         = *(const bf16x8*)(Arow + k0 + lkk);
    *(bf16x8*)&Bs[lrow * 40 + lkk]         = *(const bf16x8*)(Brow + k0 + lkk);
    *(bf16x8*)&Bs[(lrow + 64) * 40 + lkk]  = *(const bf16x8*)(Brow2 + k0 + lkk);
    __syncthreads();
    bf16x8 av[2];
    #pragma unroll
    for (int mi = 0; mi < 2; mi++) av[mi] = *(bf16x8*)&As[(wm + mi * 16 + fm) * 40 + fq * 8];
    #pragma unroll
    for (int ni = 0; ni < 4; ni++) {
      bf16x8 bv = *(bf16x8*)&Bs[(wn + ni * 16 + fm) * 40 + fq * 8];
      #pragma unroll
      for (int mi = 0; mi < 2; mi++)
        acc[mi][ni] = __builtin_amdgcn_mfma_f32_16x16x32_bf16(av[mi], bv, acc[mi][ni], 0, 0, 0);
    }
    __syncthreads();
  }
  #pragma unroll
  for (int mi = 0; mi < 2; mi++)
    #pragma unroll
    for (int ni = 0; ni < 4; ni++)
      #pragma unroll
      for (int r = 0; r < 4; r++) {
        int lr = wm + mi * 16 + fq * 4 + r;
        int gr = rt * 64 + lr;
        if (gr < ne) {
          int col = ct * 128 + wn + ni * 16 + fm;
          float val = (acc[mi][ni][r] + b2[e * 384 + col]) * lps[lr];
          ymoe[((size_t)base + gr) * 384 + col] = f2bf(val);
        }
      }
}

// ---- gather each token's two ymoe rows, add into xout (transposed layout) ----
__global__ void k_scatter(const unsigned short* __restrict__ ymoe,
                          const int* __restrict__ tpos, float* __restrict__ xout) {
  int dt_ = blockIdx.x;  // 12 tiles of 32 d
  int lt = blockIdx.y;   // 16 tiles of 64 l
  int b = blockIdx.z;    // 16
  int l = threadIdx.x & 63;
  int d0 = dt_ * 32 + (threadIdx.x >> 6) * 8;
  int n = b * 1024 + lt * 64 + l;
  int p0 = tpos[2 * n], p1 = tpos[2 * n + 1];
  bf16x8 y0 = *(const bf16x8*)(ymoe + (size_t)p0 * 384 + d0);
  bf16x8 y1 = *(const bf16x8*)(ymoe + (size_t)p1 * 384 + d0);
  size_t base = (size_t)b * DCH * LSP + (size_t)d0 * LSP + lt * 64 + l;
  #pragma unroll
  for (int k = 0; k < 8; k++) {
    float v = bf2f((unsigned short)y0[k]) + bf2f((unsigned short)y1[k]);
    xout[base + (size_t)k * LSP] += v;
  }
}

extern "C" void kernel_launch(void* const* d_in, const int* in_sizes, int n_in,
                              void* d_out, int out_size, void* d_ws, size_t ws_size,
                              hipStream_t stream) {
  const float* x      = (const float*)d_in[0];
  const float* dw1    = (const float*)d_in[1];
  const float* bn1g   = (const float*)d_in[2];
  const float* bn1b   = (const float*)d_in[3];
  const float* bn1m   = (const float*)d_in[4];
  const float* bn1v   = (const float*)d_in[5];
  const float* dw2    = (const float*)d_in[6];
  const float* bn2g   = (const float*)d_in[7];
  const float* bn2b   = (const float*)d_in[8];
  const float* bn2m   = (const float*)d_in[9];
  const float* bn2v   = (const float*)d_in[10];
  const float* lnw    = (const float*)d_in[11];
  const float* lnb    = (const float*)d_in[12];
  const float* bcdtw  = (const float*)d_in[13];
  const float* dwsw   = (const float*)d_in[14];
  const float* hprojw = (const float*)d_in[15];
  const float* Avec   = (const float*)d_in[16];
  const float* gatew  = (const float*)d_in[17];
  const float* gateb  = (const float*)d_in[18];
  const float* w1f    = (const float*)d_in[19];
  const float* b1f    = (const float*)d_in[20];
  const float* w2f    = (const float*)d_in[21];
  const float* b2f    = (const float*)d_in[22];
  const float* w3f    = (const float*)d_in[23];
  const float* b3f    = (const float*)d_in[24];

  char* wsb = (char*)d_ws;
  float* x1    = (float*)(wsb + OFF_X1);
  float* xn    = (float*)(wsb + OFF_XN);
  float* bcdt  = (float*)(wsb + OFF_BCDT);
  float* bcdtc = (float*)(wsb + OFF_BCDTC);
  float* hbuf  = (float*)(wsb + OFF_H);
  float* hpre  = (float*)(wsb + OFF_HPRE);
  float* x2    = (float*)(wsb + OFF_X2);
  float* logits = (float*)(wsb + OFF_LOGITS);
  float* probs  = (float*)(wsb + OFF_PROBS);
  int*   idx    = (int*)(wsb + OFF_IDX);
  int*   cnt    = (int*)(wsb + OFF_CNT);
  int*   fill   = (int*)(wsb + OFF_FILL);
  int*   offs   = (int*)(wsb + OFF_OFFS);
  int*   toff   = (int*)(wsb + OFF_TOFF);
  int*   ltok   = (int*)(wsb + OFF_LTOK);
  float* lp     = (float*)(wsb + OFF_LP);
  int*   tpos   = (int*)(wsb + OFF_TPOS);
  unsigned short* t16  = (unsigned short*)(wsb + OFF_T16);
  unsigned short* w1b  = (unsigned short*)(wsb + OFF_W1B);
  unsigned short* w3b  = (unsigned short*)(wsb + OFF_W3B);
  unsigned short* w2b  = (unsigned short*)(wsb + OFF_W2B);
  unsigned short* he   = (unsigned short*)(wsb + OFF_HE);
  unsigned short* ymoe = (unsigned short*)(wsb + OFF_YMOE);
  float* xout = (float*)d_out;
  float* h2   = xout + (size_t)BSZ * DCH * LSP;   // second output region

  // stage 1: x1 = x + bn1(dw1(x))
  k_dwbnres<<<BSZ * DCH, 256, 0, stream>>>(x, dw1, bn1g, bn1b, bn1m, bn1v, x1, DCH);
  // stage 2: layernorm -> xn
  k_layernorm<<<NTOK / 64, 256, 0, stream>>>(x1, lnw, lnb, xn);
  // stage 3: bcdt = bcdt_w @ xn
  k_bcdt<<<dim3(8, 3, BSZ), 256, 0, stream>>>(xn, bcdtw, bcdt);
  // stage 4: depthwise conv on bcdt
  k_dwbnres<<<BSZ * 192, 256, 0, stream>>>(bcdt, dwsw, nullptr, nullptr, nullptr, nullptr, bcdtc, 192);
  // stage 5: softmax(dt + A) over L
  k_softmax<<<BSZ * SST, 256, 0, stream>>>(bcdtc, Avec);
  // zero accumulators for split-K stages
  hipMemsetAsync(hbuf, 0, (size_t)BSZ * DCH * SST * 4, stream);
  hipMemsetAsync(hpre, 0, (size_t)BSZ * DCH * SST * 4, stream);
  // stage 6: h = xn @ (Am*Bm)^T  (L split 8-way, atomic accumulate)
  k_h<<<dim3(6, 8, BSZ), 256, 0, stream>>>(xn, bcdtc, hbuf);
  // stage 7: hpre = hproj @ h (K split 3-way, atomic), then h2 = silu(hpre)
  k_hproj<<<dim3(6, 3, BSZ), 256, 0, stream>>>(hbuf, hprojw, hpre);
  k_silu<<<(BSZ * DCH * SST / 4) / 256, 256, 0, stream>>>(hpre, h2);
  // stage 8: x2 = x1 + h2 @ Cm
  k_y<<<dim3(8, 12, BSZ), 256, 0, stream>>>(h2, bcdtc, x1, x2);
  // stage 9: x3 = x2 + bn2(dw2(x2)) -> d_out
  k_dwbnres<<<BSZ * DCH, 256, 0, stream>>>(x2, dw2, bn2g, bn2b, bn2m, bn2v, xout, DCH);
  // MoE routing
  hipMemsetAsync(wsb + OFF_CNT, 0, 64, stream);   // cnt + fill
  k_router<<<256, 256, 0, stream>>>(xout, gatew, gateb, logits);
  k_topk<<<NTOK / 256, 256, 0, stream>>>(logits, probs, idx, cnt);
  k_offsets<<<1, 64, 0, stream>>>(cnt, offs, toff);
  k_build<<<NTOK / 256, 256, 0, stream>>>(idx, probs, offs, fill, ltok, lp, tpos);
  // tokens + weights to bf16
  k_t16<<<dim3(32, 12, BSZ), 256, 0, stream>>>(xout, t16);
  int n4 = NEXP * HID * DCH / 4;
  k_f2bf3<<<dim3((n4 + 255) / 256, 3), 256, 0, stream>>>(w1f, w3f, w2f, w1b, w3b, w2b, n4);
  // MoE GEMMs: single launch each, flat (expert,row-tile) index
  k_moe1<<<dim3(MOE_MAXT, 6), 256, 0, stream>>>(t16, w1b, w3b, b1f, b3f, ltok, cnt, offs, toff, he);
  k_moe2<<<dim3(MOE_MAXT, 3), 256, 0, stream>>>(he, w2b, b2f, lp, cnt, offs, toff, ymoe);
  // gather + residual add
  k_scatter<<<dim3(12, 16, BSZ), 256, 0, stream>>>(ymoe, tpos, xout);
}

// Round 4
// 554.130 us; speedup vs baseline: 3.1571x; 1.0587x over previous
//
#include <hip/hip_runtime.h>
#include <hip/hip_bf16.h>

#define BSZ 16
#define DCH 384
#define LSP 1024
#define SST 64
#define NEXP 8
#define HID 768
#define NTOK 16384   // BSZ*LSP
#define MOE_MAXT 520 // max row tiles of 64 across experts: 32768/64 + 8

// ---- workspace byte offsets (exact-fit overlays, lifetimes checked) ----
#define OFF_X1    0ULL            // 25165824  (dead after k_y)
#define OFF_XN    25165824ULL     // 25165824  (dead after k_h)
#define OFF_BCDT  50331648ULL     // 12582912  (dead after dws conv)
#define OFF_BCDTC 62914560ULL     // 12582912  (Bm/Cm/Am; dead after k_y)
#define OFF_H     75497472ULL     // 1572864   (dead after k_hproj)
#define OFF_X2    77070336ULL     // 25165824  (dead after dwconv2)
#define OFF_META  102236160ULL    // ~1.2 MB used
#define OFF_LOGITS (OFF_META)                  // 524288
#define OFF_PROBS  (OFF_META +  524288ULL)     // 131072
#define OFF_IDX    (OFF_META +  655360ULL)     // 131072
#define OFF_CNT    (OFF_META +  786432ULL)     // 32
#define OFF_FILL   (OFF_META +  786464ULL)     // 32
#define OFF_OFFS   (OFF_META +  786496ULL)     // 32
#define OFF_TOFF   (OFF_META +  786560ULL)     // 64 (tile prefix, 9 ints)
#define OFF_LTOK   (OFF_META +  786624ULL)     // 131072
#define OFF_LP     (OFF_META +  917696ULL)     // 131072
#define OFF_TPOS   (OFF_META + 1048768ULL)     // 131072 -> ends 1179840
// overlays (used only after their hosts are dead):
#define OFF_HE    0ULL                      // 32768*768*2 = 50331648 == x1+xn
#define OFF_T16   OFF_BCDT                  // 16384*384*2 = 12582912 exact
#define OFF_W1B   OFF_BCDTC                 // 4718592
#define OFF_W3B   (OFF_BCDTC + 4718592ULL)
#define OFF_W2B   (OFF_BCDTC + 9437184ULL)  // ends exactly at OFF_X2
#define OFF_YMOE  OFF_X2                    // 32768*384*2 = 25165824 == x2 exactly
#define OFF_HPRE  OFF_X2                    // 1572864; dead before k_y writes x2

typedef __attribute__((ext_vector_type(8))) short bf16x8;
typedef __attribute__((ext_vector_type(4))) float f32x4;
typedef __attribute__((ext_vector_type(4))) unsigned short u16x4;

__device__ __forceinline__ unsigned short f2bf(float f) {
  union { float f; unsigned int u; } x; x.f = f;
  unsigned int r = (x.u + 0x7fffu + ((x.u >> 16) & 1u)) >> 16;  // RNE
  return (unsigned short)r;
}
__device__ __forceinline__ float bf2f(unsigned short s) {
  union { unsigned int u; float f; } x; x.u = ((unsigned int)s) << 16; return x.f;
}

// async global->LDS, 16 B per lane. LDS dest = base + lane*16 (wave-uniform base).
__device__ __forceinline__ void async16(const void* g, void* l) {
  unsigned long long gi = reinterpret_cast<unsigned long long>(g);
  unsigned int li = (unsigned int)reinterpret_cast<unsigned long long>(l);
  __builtin_amdgcn_global_load_lds(
      (const __attribute__((address_space(1))) unsigned int*)gi,
      (__attribute__((address_space(3))) unsigned int*)(unsigned long long)li,
      16, 0, 0);
}

// ---------------- depthwise 3x3 (+ optional BN + residual) ----------------
__global__ void k_dwbnres(const float* __restrict__ x, const float* __restrict__ w,
                          const float* __restrict__ g, const float* __restrict__ bb,
                          const float* __restrict__ mm, const float* __restrict__ vv,
                          float* __restrict__ out, int C) {
  int bc = blockIdx.x;
  int c = bc % C;
  __shared__ float tile[34 * 34];
  const float* img = x + (size_t)bc * 1024;
  for (int i = threadIdx.x; i < 34 * 34; i += 256) tile[i] = 0.f;
  __syncthreads();
  for (int i = threadIdx.x; i < 1024; i += 256) {
    int r = i >> 5, cc = i & 31;
    tile[(r + 1) * 34 + (cc + 1)] = img[i];
  }
  __syncthreads();
  float w0 = w[c*9+0], w1 = w[c*9+1], w2 = w[c*9+2], w3 = w[c*9+3], w4 = w[c*9+4],
        w5 = w[c*9+5], w6 = w[c*9+6], w7 = w[c*9+7], w8 = w[c*9+8];
  bool res = (g != nullptr);
  float scale = 1.f, bias = 0.f;
  if (res) { float s = g[c] * rsqrtf(vv[c] + 1e-5f); scale = s; bias = bb[c] - mm[c] * s; }
  for (int i = threadIdx.x; i < 1024; i += 256) {
    int r = i >> 5, cc = i & 31;
    const float* t0 = &tile[r * 34 + cc];
    float acc = t0[0]*w0 + t0[1]*w1 + t0[2]*w2
              + t0[34]*w3 + t0[35]*w4 + t0[36]*w5
              + t0[68]*w6 + t0[69]*w7 + t0[70]*w8;
    float o = res ? (t0[35] + acc * scale + bias) : acc;
    out[(size_t)bc * 1024 + i] = o;
  }
}

// ---------------- LayerNorm over channel dim of (B, D, L) ----------------
__global__ void k_layernorm(const float* __restrict__ x, const float* __restrict__ lw,
                            const float* __restrict__ lb, float* __restrict__ xn) {
  int lane = threadIdx.x & 63;
  int slice = threadIdx.x >> 6;           // 4 slices of 96 channels
  int pos0 = blockIdx.x * 64;             // 64 positions, all same b
  int b = pos0 >> 10;
  int l = (pos0 & 1023) + lane;
  const float* xb = x + (size_t)b * DCH * LSP + l;
  float s = 0.f, s2 = 0.f;
  for (int d = slice * 96; d < slice * 96 + 96; d++) {
    float v = xb[(size_t)d * LSP];
    s += v; s2 += v * v;
  }
  __shared__ float red[2][4][64];
  red[0][slice][lane] = s; red[1][slice][lane] = s2;
  __syncthreads();
  if (slice == 0) {
    s  = red[0][0][lane] + red[0][1][lane] + red[0][2][lane] + red[0][3][lane];
    s2 = red[1][0][lane] + red[1][1][lane] + red[1][2][lane] + red[1][3][lane];
    float mu = s * (1.f / 384.f);
    float var = s2 * (1.f / 384.f) - mu * mu;
    red[0][0][lane] = mu;
    red[1][0][lane] = rsqrtf(var + 1e-5f);
  }
  __syncthreads();
  float mu = red[0][0][lane], rs = red[1][0][lane];
  float* xnb = xn + (size_t)b * DCH * LSP + l;
  for (int d = slice * 96; d < slice * 96 + 96; d++) {
    float v = xb[(size_t)d * LSP];
    xnb[(size_t)d * LSP] = (v - mu) * rs * lw[d] + lb[d];
  }
}

// ---------------- bcdt = bcdt_w(192x384) @ xn(b,384,1024) ----------------
__global__ void k_bcdt(const float* __restrict__ xn, const float* __restrict__ wt,
                       float* __restrict__ out) {
  int lt = blockIdx.x, ct = blockIdx.y, b = blockIdx.z;   // (8, 3, 16)
  __shared__ float wsm[64][33];
  __shared__ float xs[32][129];
  int lg = threadIdx.x & 31, cg = threadIdx.x >> 5;
  float acc[8][4];
  for (int i = 0; i < 8; i++) for (int j = 0; j < 4; j++) acc[i][j] = 0.f;
  const float* xb = xn + (size_t)b * DCH * LSP + lt * 128;
  for (int d0 = 0; d0 < 384; d0 += 32) {
    for (int i = threadIdx.x; i < 2048; i += 256) {
      int c = i >> 5, dd = i & 31;
      wsm[c][dd] = wt[(size_t)(ct * 64 + c) * 384 + d0 + dd];
    }
    for (int i = threadIdx.x; i < 4096; i += 256) {
      int dd = i >> 7, ll = i & 127;
      xs[dd][ll] = xb[(size_t)(d0 + dd) * LSP + ll];
    }
    __syncthreads();
    for (int dd = 0; dd < 32; dd++) {
      float xv[4];
      #pragma unroll
      for (int il = 0; il < 4; il++) xv[il] = xs[dd][lg + 32 * il];
      #pragma unroll
      for (int ic = 0; ic < 8; ic++) {
        float wv = wsm[cg + 8 * ic][dd];
        #pragma unroll
        for (int il = 0; il < 4; il++) acc[ic][il] += wv * xv[il];
      }
    }
    __syncthreads();
  }
  for (int ic = 0; ic < 8; ic++)
    for (int il = 0; il < 4; il++)
      out[(size_t)b * 196608 + (size_t)(ct * 64 + cg + 8 * ic) * 1024 + lt * 128 + lg + 32 * il] = acc[ic][il];
}

// ---------------- softmax over L on dt rows (in place) ----------------
__global__ void k_softmax(float* __restrict__ bc, const float* __restrict__ Av) {
  int b = blockIdx.x >> 6, s = blockIdx.x & 63;
  float* row = bc + (size_t)b * 196608 + (size_t)(128 + s) * 1024;
  float a = Av[s];
  int t = threadIdx.x;
  float v[4]; float mx = -3.0e38f;
  #pragma unroll
  for (int i = 0; i < 4; i++) { v[i] = row[t + 256 * i] + a; mx = fmaxf(mx, v[i]); }
  #pragma unroll
  for (int off = 32; off >= 1; off >>= 1) mx = fmaxf(mx, __shfl_xor(mx, off));
  __shared__ float redm[4], reds[4];
  if ((t & 63) == 0) redm[t >> 6] = mx;
  __syncthreads();
  mx = fmaxf(fmaxf(redm[0], redm[1]), fmaxf(redm[2], redm[3]));
  float sm = 0.f;
  #pragma unroll
  for (int i = 0; i < 4; i++) { v[i] = __expf(v[i] - mx); sm += v[i]; }
  #pragma unroll
  for (int off = 32; off >= 1; off >>= 1) sm += __shfl_xor(sm, off);
  if ((t & 63) == 0) reds[t >> 6] = sm;
  __syncthreads();
  sm = reds[0] + reds[1] + reds[2] + reds[3];
  float inv = 1.f / sm;
  #pragma unroll
  for (int i = 0; i < 4; i++) row[t + 256 * i] = v[i] * inv;
}

// ---- h[b,d,s] += sum_{l in chunk} xn[b,d,l] * (Am*Bm)[b,s,l]; L split 8-way ----
__global__ void k_h(const float* __restrict__ xn, const float* __restrict__ bc,
                    float* __restrict__ h) {
  int dt_ = blockIdx.x, ls = blockIdx.y, b = blockIdx.z;   // (6, 8, 16)
  __shared__ float xs[64][65];
  __shared__ float ab[64][65];
  int tid = threadIdx.x;
  int sg4 = tid & 15, dg4 = tid >> 4;     // 16x16 thread grid, 4x4 regs each
  float acc[4][4];
  #pragma unroll
  for (int i = 0; i < 4; i++)
    #pragma unroll
    for (int j = 0; j < 4; j++) acc[i][j] = 0.f;
  const float* Bm = bc + (size_t)b * 196608;
  const float* Am = Bm + 131072;
  const float* xb = xn + (size_t)b * DCH * LSP + (size_t)(dt_ * 64) * LSP;
  for (int l0 = ls * 128; l0 < ls * 128 + 128; l0 += 64) {
    for (int i = tid; i < 4096; i += 256) {
      int r = i >> 6, ll = i & 63;
      xs[r][ll] = xb[(size_t)r * LSP + l0 + ll];
      ab[r][ll] = Am[(size_t)r * 1024 + l0 + ll] * Bm[(size_t)r * 1024 + l0 + ll];
    }
    __syncthreads();
    for (int ll = 0; ll < 64; ll++) {
      float xv[4], av[4];
      #pragma unroll
      for (int i = 0; i < 4; i++) xv[i] = xs[dg4 * 4 + i][ll];
      #pragma unroll
      for (int j = 0; j < 4; j++) av[j] = ab[sg4 * 4 + j][ll];
      #pragma unroll
      for (int i = 0; i < 4; i++)
        #pragma unroll
        for (int j = 0; j < 4; j++) acc[i][j] += xv[i] * av[j];
    }
    __syncthreads();
  }
  float* hb = h + (size_t)b * DCH * SST + (size_t)(dt_ * 64) * 64;
  #pragma unroll
  for (int i = 0; i < 4; i++)
    #pragma unroll
    for (int j = 0; j < 4; j++)
      atomicAdd(&hb[(size_t)(dg4 * 4 + i) * 64 + sg4 * 4 + j], acc[i][j]);
}

// ---- hpre[b,e,s] += sum_{d in chunk} pw[e,d]*h[b,d,s]; K split 3-way ----
__global__ void k_hproj(const float* __restrict__ h, const float* __restrict__ pw,
                        float* __restrict__ hpre) {
  int et = blockIdx.x, ks = blockIdx.y, b = blockIdx.z;   // (6, 3, 16)
  __shared__ float hs[64][65];   // [d][s]
  __shared__ float ps[64][65];   // [e][d]
  int tid = threadIdx.x;
  int sg4 = tid & 15, eg4 = tid >> 4;
  float acc[4][4];
  #pragma unroll
  for (int i = 0; i < 4; i++)
    #pragma unroll
    for (int j = 0; j < 4; j++) acc[i][j] = 0.f;
  for (int d0 = ks * 128; d0 < ks * 128 + 128; d0 += 64) {
    for (int i = tid; i < 4096; i += 256) {
      int r = i >> 6, cc = i & 63;
      hs[r][cc] = h[(size_t)b * DCH * SST + (size_t)(d0 + r) * 64 + cc];
      ps[r][cc] = pw[(size_t)(et * 64 + r) * 384 + d0 + cc];
    }
    __syncthreads();
    for (int dd = 0; dd < 64; dd++) {
      float pv[4], hv[4];
      #pragma unroll
      for (int i = 0; i < 4; i++) pv[i] = ps[eg4 * 4 + i][dd];
      #pragma unroll
      for (int j = 0; j < 4; j++) hv[j] = hs[dd][sg4 * 4 + j];
      #pragma unroll
      for (int i = 0; i < 4; i++)
        #pragma unroll
        for (int j = 0; j < 4; j++) acc[i][j] += pv[i] * hv[j];
    }
    __syncthreads();
  }
  float* hb = hpre + (size_t)b * DCH * SST + (size_t)(et * 64) * 64;
  #pragma unroll
  for (int i = 0; i < 4; i++)
    #pragma unroll
    for (int j = 0; j < 4; j++)
      atomicAdd(&hb[(size_t)(eg4 * 4 + i) * 64 + sg4 * 4 + j], acc[i][j]);
}

// ---- h2 = silu(hpre), vectorized ----
__global__ void k_silu(const float* __restrict__ hpre, float* __restrict__ h2) {
  int i = blockIdx.x * 256 + threadIdx.x;   // over 98304 float4s
  float4 v = ((const float4*)hpre)[i];
  v.x = v.x / (1.f + __expf(-v.x));
  v.y = v.y / (1.f + __expf(-v.y));
  v.z = v.z / (1.f + __expf(-v.z));
  v.w = v.w / (1.f + __expf(-v.w));
  ((float4*)h2)[i] = v;
}

// ---------------- x2 = x1 + h2 @ Cm ----------------
__global__ void k_y(const float* __restrict__ h2, const float* __restrict__ bc,
                    const float* __restrict__ x1, float* __restrict__ x2) {
  int lt = blockIdx.x, dt_ = blockIdx.y, b = blockIdx.z;   // (8, 12, 16)
  __shared__ float hss[32][65];
  __shared__ float cs[64][129];
  int lg = threadIdx.x & 31, dg = threadIdx.x >> 5;
  float acc[4][4];
  for (int i = 0; i < 4; i++) for (int j = 0; j < 4; j++) acc[i][j] = 0.f;
  for (int i = threadIdx.x; i < 2048; i += 256) {
    int r = i >> 6, cc = i & 63;
    hss[r][cc] = h2[(size_t)b * DCH * SST + (size_t)(dt_ * 32 + r) * 64 + cc];
  }
  const float* Cm = bc + (size_t)b * 196608 + 65536;
  for (int i = threadIdx.x; i < 8192; i += 256) {
    int ss = i >> 7, ll = i & 127;
    cs[ss][ll] = Cm[(size_t)ss * 1024 + lt * 128 + ll];
  }
  __syncthreads();
  for (int ss = 0; ss < 64; ss++) {
    float cv[4];
    #pragma unroll
    for (int il = 0; il < 4; il++) cv[il] = cs[ss][lg + 32 * il];
    #pragma unroll
    for (int id = 0; id < 4; id++) {
      float hv = hss[dg * 4 + id][ss];
      #pragma unroll
      for (int il = 0; il < 4; il++) acc[id][il] += hv * cv[il];
    }
  }
  size_t base = (size_t)b * DCH * LSP + (size_t)(dt_ * 32) * LSP + lt * 128;
  for (int id = 0; id < 4; id++)
    for (int il = 0; il < 4; il++) {
      size_t o = base + (size_t)(dg * 4 + id) * LSP + lg + 32 * il;
      x2[o] = x1[o] + acc[id][il];
    }
}

// ---------------- router logits ----------------
__global__ void k_router(const float* __restrict__ x3, const float* __restrict__ gw,
                         const float* __restrict__ gb, float* __restrict__ logits) {
  __shared__ float xs[64][65];
  __shared__ float gs[8][64];
  int blk = blockIdx.x;                  // 256 blocks of 64 tokens
  int b = blk >> 4; int l0 = (blk & 15) * 64;
  int lg = threadIdx.x & 63, eg = threadIdx.x >> 6;
  float acc0 = 0.f, acc1 = 0.f;
  const float* xb = x3 + (size_t)b * DCH * LSP + l0;
  for (int d0 = 0; d0 < 384; d0 += 64) {
    for (int i = threadIdx.x; i < 4096; i += 256) {
      int dd = i >> 6, ll = i & 63;
      xs[dd][ll] = xb[(size_t)(d0 + dd) * LSP + ll];
    }
    for (int i = threadIdx.x; i < 512; i += 256) {
      int e = i >> 6, dd = i & 63;
      gs[e][dd] = gw[(size_t)e * 384 + d0 + dd];
    }
    __syncthreads();
    for (int dd = 0; dd < 64; dd++) {
      float xv = xs[dd][lg];
      acc0 += gs[eg][dd] * xv;
      acc1 += gs[eg + 4][dd] * xv;
    }
    __syncthreads();
  }
  int n = b * 1024 + l0 + lg;
  logits[(size_t)n * 8 + eg]     = acc0 + gb[eg];
  logits[(size_t)n * 8 + eg + 4] = acc1 + gb[eg + 4];
}

// ---------------- top-2 + softmax + counts (LDS-aggregated atomics) ----------------
__global__ void k_topk(const float* __restrict__ logits, float* __restrict__ probs,
                       int* __restrict__ idx, int* __restrict__ cnt) {
  __shared__ int lcnt[8];
  if (threadIdx.x < 8) lcnt[threadIdx.x] = 0;
  __syncthreads();
  int n = blockIdx.x * 256 + threadIdx.x;
  float lv[8];
  for (int e = 0; e < 8; e++) lv[e] = logits[(size_t)n * 8 + e];
  int i1 = 0; float v1 = lv[0];
  for (int e = 1; e < 8; e++) if (lv[e] > v1) { v1 = lv[e]; i1 = e; }
  int i2 = -1; float v2 = -3.0e38f;
  for (int e = 0; e < 8; e++) { if (e == i1) continue; if (lv[e] > v2) { v2 = lv[e]; i2 = e; } }
  float p1 = 1.f / (1.f + __expf(v2 - v1));
  probs[n * 2] = p1; probs[n * 2 + 1] = 1.f - p1;
  idx[n * 2] = i1; idx[n * 2 + 1] = i2;
  atomicAdd(&lcnt[i1], 1); atomicAdd(&lcnt[i2], 1);
  __syncthreads();
  if (threadIdx.x < 8) atomicAdd(&cnt[threadIdx.x], lcnt[threadIdx.x]);
}

__global__ void k_offsets(const int* __restrict__ cnt, int* __restrict__ offs,
                          int* __restrict__ toff) {
  if (threadIdx.x == 0) {
    int a = 0, t = 0;
    for (int e = 0; e < 8; e++) {
      offs[e] = a; toff[e] = t;
      a += cnt[e]; t += (cnt[e] + 63) >> 6;
    }
    toff[8] = t;
  }
}

// ---------------- build expert token lists (LDS-aggregated) ----------------
__global__ void k_build(const int* __restrict__ idx, const float* __restrict__ probs,
                        const int* __restrict__ offs, int* __restrict__ fill,
                        int* __restrict__ ltok, float* __restrict__ lp,
                        int* __restrict__ tpos) {
  __shared__ int lcnt[8], lbase[8];
  if (threadIdx.x < 8) lcnt[threadIdx.x] = 0;
  __syncthreads();
  int n = blockIdx.x * 256 + threadIdx.x;
  int e0 = idx[n * 2], e1 = idx[n * 2 + 1];
  int o0 = atomicAdd(&lcnt[e0], 1);
  int o1 = atomicAdd(&lcnt[e1], 1);
  __syncthreads();
  if (threadIdx.x < 8) lbase[threadIdx.x] = atomicAdd(&fill[threadIdx.x], lcnt[threadIdx.x]);
  __syncthreads();
  int p0 = offs[e0] + lbase[e0] + o0;
  int p1 = offs[e1] + lbase[e1] + o1;
  ltok[p0] = n; lp[p0] = probs[n * 2];     tpos[n * 2] = p0;
  ltok[p1] = n; lp[p1] = probs[n * 2 + 1]; tpos[n * 2 + 1] = p1;
}

// ---------------- tokens -> bf16 [N][D] (transpose) ----------------
__global__ void k_t16(const float* __restrict__ x3, unsigned short* __restrict__ t16) {
  __shared__ float tl[32][33];
  int lt = blockIdx.x, dt_ = blockIdx.y, b = blockIdx.z;   // (32, 12, 16)
  const float* xb = x3 + (size_t)b * DCH * LSP + (size_t)(dt_ * 32) * LSP + lt * 32;
  for (int i = threadIdx.x; i < 1024; i += 256) {
    int dd = i >> 5, ll = i & 31;
    tl[dd][ll] = xb[(size_t)dd * LSP + ll];
  }
  __syncthreads();
  for (int i = threadIdx.x; i < 1024; i += 256) {
    int ll = i >> 5, dd = i & 31;
    int n = b * 1024 + lt * 32 + ll;
    t16[(size_t)n * 384 + dt_ * 32 + dd] = f2bf(tl[dd][ll]);
  }
}

// ---------------- 3 weight arrays fp32 -> bf16, vectorized ----------------
__global__ void k_f2bf3(const float* __restrict__ s0, const float* __restrict__ s1,
                        const float* __restrict__ s2, unsigned short* __restrict__ d0,
                        unsigned short* __restrict__ d1, unsigned short* __restrict__ d2,
                        int n4) {
  int i = blockIdx.x * 256 + threadIdx.x;
  if (i >= n4) return;
  const float* s = (blockIdx.y == 0) ? s0 : (blockIdx.y == 1) ? s1 : s2;
  unsigned short* d = (blockIdx.y == 0) ? d0 : (blockIdx.y == 1) ? d1 : d2;
  float4 v = ((const float4*)s)[i];
  u16x4 o;
  o.x = f2bf(v.x); o.y = f2bf(v.y); o.z = f2bf(v.z); o.w = f2bf(v.w);
  ((u16x4*)d)[i] = o;
}

// ---- MoE GEMM1: he = silu(t@w1^T+b1)*(t@w3^T+b3); 64x128 tile, BK=64,
//      XOR-swizzled LDS (stride 64 ushorts, slot = chunk ^ (row&7)),
//      async global_load_lds staging ----
__global__ void __launch_bounds__(256) k_moe1(
    const unsigned short* __restrict__ t16, const unsigned short* __restrict__ w1,
    const unsigned short* __restrict__ w3, const float* __restrict__ b1,
    const float* __restrict__ b3, const int* __restrict__ ltok,
    const int* __restrict__ cnt, const int* __restrict__ offs,
    const int* __restrict__ toff, unsigned short* __restrict__ he) {
  int tb = blockIdx.x;
  if (tb >= toff[8]) return;
  int e = 0;
  #pragma unroll
  for (int i = 1; i < 8; i++) if (toff[i] <= tb) e = i;
  int rt = tb - toff[e];
  int ne = cnt[e], base = offs[e];
  int ct = blockIdx.y;                  // 6 col tiles of 128 over HID
  __shared__ unsigned short As[64 * 64];     // 8 KB
  __shared__ unsigned short B1s[128 * 64];   // 16 KB
  __shared__ unsigned short B3s[128 * 64];   // 16 KB
  __shared__ int toks[64];
  int tid = threadIdx.x;
  if (tid < 64) {
    int r = rt * 64 + tid;
    toks[tid] = ltok[base + (r < ne ? r : ne - 1)];
  }
  __syncthreads();
  int lane = tid & 63, wave = tid >> 6;
  int wm = (wave & 1) * 32, wn = (wave >> 1) * 64;
  int fm = lane & 15, fq = lane >> 4;
  int srow = lane >> 3, slot = lane & 7;
  f32x4 acc1[2][4], acc3[2][4];
  #pragma unroll
  for (int mi = 0; mi < 2; mi++)
    #pragma unroll
    for (int ni = 0; ni < 4; ni++) { acc1[mi][ni] = (f32x4)(0.f); acc3[mi][ni] = (f32x4)(0.f); }
  const unsigned short* w1e = w1 + ((size_t)e * 768 + ct * 128) * 384;
  const unsigned short* w3e = w3 + ((size_t)e * 768 + ct * 128) * 384;
  // per-lane global base pointers for staging (k0 added in loop)
  int ar0 = wave * 16 + srow, ar1 = wave * 16 + 8 + srow;
  const unsigned short* ag0 = t16 + (size_t)toks[ar0] * 384 + ((slot ^ (ar0 & 7)) * 8);
  const unsigned short* ag1 = t16 + (size_t)toks[ar1] * 384 + ((slot ^ (ar1 & 7)) * 8);
  const unsigned short* b1g[4]; const unsigned short* b3g[4];
  #pragma unroll
  for (int ii = 0; ii < 4; ii++) {
    int brow = wave * 32 + ii * 8 + srow;
    int coff = (slot ^ (brow & 7)) * 8;
    b1g[ii] = w1e + (size_t)brow * 384 + coff;
    b3g[ii] = w3e + (size_t)brow * 384 + coff;
  }
  unsigned short* asw0 = &As[(wave * 16) * 64];
  unsigned short* asw1 = &As[(wave * 16 + 8) * 64];
  for (int k0 = 0; k0 < 384; k0 += 64) {
    async16(ag0 + k0, asw0);
    async16(ag1 + k0, asw1);
    #pragma unroll
    for (int ii = 0; ii < 4; ii++) {
      async16(b1g[ii] + k0, &B1s[(wave * 32 + ii * 8) * 64]);
      async16(b3g[ii] + k0, &B3s[(wave * 32 + ii * 8) * 64]);
    }
    __syncthreads();
    #pragma unroll
    for (int kk = 0; kk < 2; kk++) {
      int c = kk * 4 + fq;
      bf16x8 av[2];
      #pragma unroll
      for (int mi = 0; mi < 2; mi++) {
        int row = wm + mi * 16 + fm;
        av[mi] = *(bf16x8*)&As[row * 64 + ((c ^ (row & 7)) * 8)];
      }
      #pragma unroll
      for (int ni = 0; ni < 4; ni++) {
        int row = wn + ni * 16 + fm;
        int off = row * 64 + ((c ^ (row & 7)) * 8);
        bf16x8 b1v = *(bf16x8*)&B1s[off];
        bf16x8 b3v = *(bf16x8*)&B3s[off];
        #pragma unroll
        for (int mi = 0; mi < 2; mi++) {
          acc1[mi][ni] = __builtin_amdgcn_mfma_f32_16x16x32_bf16(av[mi], b1v, acc1[mi][ni], 0, 0, 0);
          acc3[mi][ni] = __builtin_amdgcn_mfma_f32_16x16x32_bf16(av[mi], b3v, acc3[mi][ni], 0, 0, 0);
        }
      }
    }
    __syncthreads();
  }
  #pragma unroll
  for (int mi = 0; mi < 2; mi++)
    #pragma unroll
    for (int ni = 0; ni < 4; ni++)
      #pragma unroll
      for (int r = 0; r < 4; r++) {
        int lr = wm + mi * 16 + fq * 4 + r;
        int gr = rt * 64 + lr;
        if (gr < ne) {
          int col = ct * 128 + wn + ni * 16 + fm;
          float z1 = acc1[mi][ni][r] + b1[e * 768 + col];
          float z3 = acc3[mi][ni][r] + b3[e * 768 + col];
          float val = (z1 / (1.f + __expf(-z1))) * z3;
          he[((size_t)base + gr) * 768 + col] = f2bf(val);
        }
      }
}

// ---- MoE GEMM2: ymoe[pos][col] = (he@w2^T + b2) * lp; same structure, K=768 ----
__global__ void __launch_bounds__(256) k_moe2(
    const unsigned short* __restrict__ he, const unsigned short* __restrict__ w2,
    const float* __restrict__ b2, const float* __restrict__ lp,
    const int* __restrict__ cnt, const int* __restrict__ offs,
    const int* __restrict__ toff, unsigned short* __restrict__ ymoe) {
  int tb = blockIdx.x;
  if (tb >= toff[8]) return;
  int e = 0;
  #pragma unroll
  for (int i = 1; i < 8; i++) if (toff[i] <= tb) e = i;
  int rt = tb - toff[e];
  int ne = cnt[e], base = offs[e];
  int ct = blockIdx.y;                  // 3 col tiles of 128 over D
  __shared__ unsigned short As[64 * 64];    // 8 KB
  __shared__ unsigned short Bs[128 * 64];   // 16 KB
  __shared__ float lps[64];
  int tid = threadIdx.x;
  if (tid < 64) {
    int r = rt * 64 + tid;
    lps[tid] = lp[base + (r < ne ? r : ne - 1)];
  }
  int lane = tid & 63, wave = tid >> 6;
  int wm = (wave & 1) * 32, wn = (wave >> 1) * 64;
  int fm = lane & 15, fq = lane >> 4;
  int srow = lane >> 3, slot = lane & 7;
  f32x4 acc[2][4];
  #pragma unroll
  for (int mi = 0; mi < 2; mi++)
    #pragma unroll
    for (int ni = 0; ni < 4; ni++) acc[mi][ni] = (f32x4)(0.f);
  const unsigned short* w2e = w2 + ((size_t)e * 384 + ct * 128) * 768;
  int ar0 = wave * 16 + srow, ar1 = wave * 16 + 8 + srow;
  int g0 = base + rt * 64 + ar0; if (g0 > 32767) g0 = 32767;
  int g1 = base + rt * 64 + ar1; if (g1 > 32767) g1 = 32767;
  const unsigned short* ag0 = he + (size_t)g0 * 768 + ((slot ^ (ar0 & 7)) * 8);
  const unsigned short* ag1 = he + (size_t)g1 * 768 + ((slot ^ (ar1 & 7)) * 8);
  const unsigned short* bg[4];
  #pragma unroll
  for (int ii = 0; ii < 4; ii++) {
    int brow = wave * 32 + ii * 8 + srow;
    bg[ii] = w2e + (size_t)brow * 768 + ((slot ^ (brow & 7)) * 8);
  }
  unsigned short* asw0 = &As[(wave * 16) * 64];
  unsigned short* asw1 = &As[(wave * 16 + 8) * 64];
  for (int k0 = 0; k0 < 768; k0 += 64) {
    async16(ag0 + k0, asw0);
    async16(ag1 + k0, asw1);
    #pragma unroll
    for (int ii = 0; ii < 4; ii++)
      async16(bg[ii] + k0, &Bs[(wave * 32 + ii * 8) * 64]);
    __syncthreads();
    #pragma unroll
    for (int kk = 0; kk < 2; kk++) {
      int c = kk * 4 + fq;
      bf16x8 av[2];
      #pragma unroll
      for (int mi = 0; mi < 2; mi++) {
        int row = wm + mi * 16 + fm;
        av[mi] = *(bf16x8*)&As[row * 64 + ((c ^ (row & 7)) * 8)];
      }
      #pragma unroll
      for (int ni = 0; ni < 4; ni++) {
        int row = wn + ni * 16 + fm;
        bf16x8 bv = *(bf16x8*)&Bs[row * 64 + ((c ^ (row & 7)) * 8)];
        #pragma unroll
        for (int mi = 0; mi < 2; mi++)
          acc[mi][ni] = __builtin_amdgcn_mfma_f32_16x16x32_bf16(av[mi], bv, acc[mi][ni], 0, 0, 0);
      }
    }
    __syncthreads();
  }
  #pragma unroll
  for (int mi = 0; mi < 2; mi++)
    #pragma unroll
    for (int ni = 0; ni < 4; ni++)
      #pragma unroll
      for (int r = 0; r < 4; r++) {
        int lr = wm + mi * 16 + fq * 4 + r;
        int gr = rt * 64 + lr;
        if (gr < ne) {
          int col = ct * 128 + wn + ni * 16 + fm;
          float val = (acc[mi][ni][r] + b2[e * 384 + col]) * lps[lr];
          ymoe[((size_t)base + gr) * 384 + col] = f2bf(val);
        }
      }
}

// ---- gather each token's two ymoe rows, add into xout (transposed layout) ----
__global__ void k_scatter(const unsigned short* __restrict__ ymoe,
                          const int* __restrict__ tpos, float* __restrict__ xout) {
  int dt_ = blockIdx.x;  // 12 tiles of 32 d
  int lt = blockIdx.y;   // 16 tiles of 64 l
  int b = blockIdx.z;    // 16
  int l = threadIdx.x & 63;
  int d0 = dt_ * 32 + (threadIdx.x >> 6) * 8;
  int n = b * 1024 + lt * 64 + l;
  int p0 = tpos[2 * n], p1 = tpos[2 * n + 1];
  bf16x8 y0 = *(const bf16x8*)(ymoe + (size_t)p0 * 384 + d0);
  bf16x8 y1 = *(const bf16x8*)(ymoe + (size_t)p1 * 384 + d0);
  size_t base = (size_t)b * DCH * LSP + (size_t)d0 * LSP + lt * 64 + l;
  #pragma unroll
  for (int k = 0; k < 8; k++) {
    float v = bf2f((unsigned short)y0[k]) + bf2f((unsigned short)y1[k]);
    xout[base + (size_t)k * LSP] += v;
  }
}

extern "C" void kernel_launch(void* const* d_in, const int* in_sizes, int n_in,
                              void* d_out, int out_size, void* d_ws, size_t ws_size,
                              hipStream_t stream) {
  const float* x      = (const float*)d_in[0];
  const float* dw1    = (const float*)d_in[1];
  const float* bn1g   = (const float*)d_in[2];
  const float* bn1b   = (const float*)d_in[3];
  const float* bn1m   = (const float*)d_in[4];
  const float* bn1v   = (const float*)d_in[5];
  const float* dw2    = (const float*)d_in[6];
  const float* bn2g   = (const float*)d_in[7];
  const float* bn2b   = (const float*)d_in[8];
  const float* bn2m   = (const float*)d_in[9];
  const float* bn2v   = (const float*)d_in[10];
  const float* lnw    = (const float*)d_in[11];
  const float* lnb    = (const float*)d_in[12];
  const float* bcdtw  = (const float*)d_in[13];
  const float* dwsw   = (const float*)d_in[14];
  const float* hprojw = (const float*)d_in[15];
  const float* Avec   = (const float*)d_in[16];
  const float* gatew  = (const float*)d_in[17];
  const float* gateb  = (const float*)d_in[18];
  const float* w1f    = (const float*)d_in[19];
  const float* b1f    = (const float*)d_in[20];
  const float* w2f    = (const float*)d_in[21];
  const float* b2f    = (const float*)d_in[22];
  const float* w3f    = (const float*)d_in[23];
  const float* b3f    = (const float*)d_in[24];

  char* wsb = (char*)d_ws;
  float* x1    = (float*)(wsb + OFF_X1);
  float* xn    = (float*)(wsb + OFF_XN);
  float* bcdt  = (float*)(wsb + OFF_BCDT);
  float* bcdtc = (float*)(wsb + OFF_BCDTC);
  float* hbuf  = (float*)(wsb + OFF_H);
  float* hpre  = (float*)(wsb + OFF_HPRE);
  float* x2    = (float*)(wsb + OFF_X2);
  float* logits = (float*)(wsb + OFF_LOGITS);
  float* probs  = (float*)(wsb + OFF_PROBS);
  int*   idx    = (int*)(wsb + OFF_IDX);
  int*   cnt    = (int*)(wsb + OFF_CNT);
  int*   fill   = (int*)(wsb + OFF_FILL);
  int*   offs   = (int*)(wsb + OFF_OFFS);
  int*   toff   = (int*)(wsb + OFF_TOFF);
  int*   ltok   = (int*)(wsb + OFF_LTOK);
  float* lp     = (float*)(wsb + OFF_LP);
  int*   tpos   = (int*)(wsb + OFF_TPOS);
  unsigned short* t16  = (unsigned short*)(wsb + OFF_T16);
  unsigned short* w1b  = (unsigned short*)(wsb + OFF_W1B);
  unsigned short* w3b  = (unsigned short*)(wsb + OFF_W3B);
  unsigned short* w2b  = (unsigned short*)(wsb + OFF_W2B);
  unsigned short* he   = (unsigned short*)(wsb + OFF_HE);
  unsigned short* ymoe = (unsigned short*)(wsb + OFF_YMOE);
  float* xout = (float*)d_out;
  float* h2   = xout + (size_t)BSZ * DCH * LSP;   // second output region

  // stage 1: x1 = x + bn1(dw1(x))
  k_dwbnres<<<BSZ * DCH, 256, 0, stream>>>(x, dw1, bn1g, bn1b, bn1m, bn1v, x1, DCH);
  // stage 2: layernorm -> xn
  k_layernorm<<<NTOK / 64, 256, 0, stream>>>(x1, lnw, lnb, xn);
  // stage 3: bcdt = bcdt_w @ xn
  k_bcdt<<<dim3(8, 3, BSZ), 256, 0, stream>>>(xn, bcdtw, bcdt);
  // stage 4: depthwise conv on bcdt
  k_dwbnres<<<BSZ * 192, 256, 0, stream>>>(bcdt, dwsw, nullptr, nullptr, nullptr, nullptr, bcdtc, 192);
  // stage 5: softmax(dt + A) over L
  k_softmax<<<BSZ * SST, 256, 0, stream>>>(bcdtc, Avec);
  // zero accumulators for split-K stages
  hipMemsetAsync(hbuf, 0, (size_t)BSZ * DCH * SST * 4, stream);
  hipMemsetAsync(hpre, 0, (size_t)BSZ * DCH * SST * 4, stream);
  // stage 6: h = xn @ (Am*Bm)^T  (L split 8-way, atomic accumulate)
  k_h<<<dim3(6, 8, BSZ), 256, 0, stream>>>(xn, bcdtc, hbuf);
  // stage 7: hpre = hproj @ h (K split 3-way, atomic), then h2 = silu(hpre)
  k_hproj<<<dim3(6, 3, BSZ), 256, 0, stream>>>(hbuf, hprojw, hpre);
  k_silu<<<(BSZ * DCH * SST / 4) / 256, 256, 0, stream>>>(hpre, h2);
  // stage 8: x2 = x1 + h2 @ Cm
  k_y<<<dim3(8, 12, BSZ), 256, 0, stream>>>(h2, bcdtc, x1, x2);
  // stage 9: x3 = x2 + bn2(dw2(x2)) -> d_out
  k_dwbnres<<<BSZ * DCH, 256, 0, stream>>>(x2, dw2, bn2g, bn2b, bn2m, bn2v, xout, DCH);
  // MoE routing
  hipMemsetAsync(wsb + OFF_CNT, 0, 64, stream);   // cnt + fill
  k_router<<<256, 256, 0, stream>>>(xout, gatew, gateb, logits);
  k_topk<<<NTOK / 256, 256, 0, stream>>>(logits, probs, idx, cnt);
  k_offsets<<<1, 64, 0, stream>>>(cnt, offs, toff);
  k_build<<<NTOK / 256, 256, 0, stream>>>(idx, probs, offs, fill, ltok, lp, tpos);
  // tokens + weights to bf16
  k_t16<<<dim3(32, 12, BSZ), 256, 0, stream>>>(xout, t16);
  int n4 = NEXP * HID * DCH / 4;
  k_f2bf3<<<dim3((n4 + 255) / 256, 3), 256, 0, stream>>>(w1f, w3f, w2f, w1b, w3b, w2b, n4);
  // MoE GEMMs: single launch each, flat (expert,row-tile) index
  k_moe1<<<dim3(MOE_MAXT, 6), 256, 0, stream>>>(t16, w1b, w3b, b1f, b3f, ltok, cnt, offs, toff, he);
  k_moe2<<<dim3(MOE_MAXT, 3), 256, 0, stream>>>(he, w2b, b2f, lp, cnt, offs, toff, ymoe);
  // gather + residual add
  k_scatter<<<dim3(12, 16, BSZ), 256, 0, stream>>>(ymoe, tpos, xout);
}

// Round 5
// 505.597 us; speedup vs baseline: 3.4602x; 1.0960x over previous
//
#include <hip/hip_runtime.h>
#include <hip/hip_bf16.h>

#define BSZ 16
#define DCH 384
#define LSP 1024
#define SST 64
#define NEXP 8
#define HID 768
#define NTOK 16384   // BSZ*LSP
#define MOE_MAXT 520 // max row tiles of 64 across experts: 32768/64 + 8

// ---- workspace byte offsets (exact-fit overlays, lifetimes checked) ----
#define OFF_X1    0ULL            // 25165824  (dead after k_y)
#define OFF_XN    25165824ULL     // 25165824  (dead after k_h)
#define OFF_BCDT  50331648ULL     // 12582912  (dead after dws conv)
#define OFF_BCDTC 62914560ULL     // 12582912  (Bm/Cm/Am; dead after k_y)
#define OFF_H     75497472ULL     // 1572864   (dead after k_hproj)
#define OFF_X2    77070336ULL     // 25165824  (dead after dwconv2)
#define OFF_META  102236160ULL    // ~1.35 MB used
#define OFF_LOGITS (OFF_META)                  // 524288
#define OFF_PROBS  (OFF_META +  524288ULL)     // 131072
#define OFF_IDX    (OFF_META +  655360ULL)     // 131072
#define OFF_CNT    (OFF_META +  786432ULL)     // 32
#define OFF_FILL   (OFF_META +  786464ULL)     // 32
#define OFF_OFFS   (OFF_META +  786496ULL)     // 32
#define OFF_TOFF   (OFF_META +  786560ULL)     // 64 (tile prefix, 9 ints)
#define OFF_LTOK   (OFF_META +  786624ULL)     // 131072
#define OFF_LP     (OFF_META +  917696ULL)     // 131072
#define OFF_TPOS   (OFF_META + 1048768ULL)     // 131072 -> ends 1179840
#define OFF_WBC    (OFF_META + 1179840ULL)     // 147456 (bcdt_w bf16) -> ends 1327296
// overlays (used only after their hosts are dead):
#define OFF_HE    0ULL                      // 32768*768*2 = 50331648 == x1+xn
#define OFF_T16   OFF_BCDT                  // 16384*384*2 = 12582912 exact
#define OFF_W1B   OFF_BCDTC                 // 4718592
#define OFF_W3B   (OFF_BCDTC + 4718592ULL)
#define OFF_W2B   (OFF_BCDTC + 9437184ULL)  // ends exactly at OFF_X2
#define OFF_YMOE  OFF_X2                    // 32768*384*2 = 25165824 == x2 exactly
#define OFF_HPRE  OFF_X2                    // 1572864; dead before k_y writes x2
#define OFF_XNT   OFF_X2                    // 12582912; xn bf16 transposed, dead after k_bcdt (before hpre/ymoe/x2 live)

typedef __attribute__((ext_vector_type(8))) short bf16x8;
typedef __attribute__((ext_vector_type(4))) float f32x4;
typedef __attribute__((ext_vector_type(4))) unsigned short u16x4;

__device__ __forceinline__ unsigned short f2bf(float f) {
  union { float f; unsigned int u; } x; x.f = f;
  unsigned int r = (x.u + 0x7fffu + ((x.u >> 16) & 1u)) >> 16;  // RNE
  return (unsigned short)r;
}
__device__ __forceinline__ float bf2f(unsigned short s) {
  union { unsigned int u; float f; } x; x.u = ((unsigned int)s) << 16; return x.f;
}

// async global->LDS, 16 B per lane. LDS dest = base + lane*16 (wave-uniform base).
__device__ __forceinline__ void async16(const void* g, void* l) {
  unsigned long long gi = reinterpret_cast<unsigned long long>(g);
  unsigned int li = (unsigned int)reinterpret_cast<unsigned long long>(l);
  __builtin_amdgcn_global_load_lds(
      (const __attribute__((address_space(1))) unsigned int*)gi,
      (__attribute__((address_space(3))) unsigned int*)(unsigned long long)li,
      16, 0, 0);
}

// ---------------- depthwise 3x3 (+ optional BN + residual) ----------------
__global__ void k_dwbnres(const float* __restrict__ x, const float* __restrict__ w,
                          const float* __restrict__ g, const float* __restrict__ bb,
                          const float* __restrict__ mm, const float* __restrict__ vv,
                          float* __restrict__ out, int C) {
  int bc = blockIdx.x;
  int c = bc % C;
  __shared__ float tile[34 * 34];
  const float* img = x + (size_t)bc * 1024;
  for (int i = threadIdx.x; i < 34 * 34; i += 256) tile[i] = 0.f;
  __syncthreads();
  for (int i = threadIdx.x; i < 1024; i += 256) {
    int r = i >> 5, cc = i & 31;
    tile[(r + 1) * 34 + (cc + 1)] = img[i];
  }
  __syncthreads();
  float w0 = w[c*9+0], w1 = w[c*9+1], w2 = w[c*9+2], w3 = w[c*9+3], w4 = w[c*9+4],
        w5 = w[c*9+5], w6 = w[c*9+6], w7 = w[c*9+7], w8 = w[c*9+8];
  bool res = (g != nullptr);
  float scale = 1.f, bias = 0.f;
  if (res) { float s = g[c] * rsqrtf(vv[c] + 1e-5f); scale = s; bias = bb[c] - mm[c] * s; }
  for (int i = threadIdx.x; i < 1024; i += 256) {
    int r = i >> 5, cc = i & 31;
    const float* t0 = &tile[r * 34 + cc];
    float acc = t0[0]*w0 + t0[1]*w1 + t0[2]*w2
              + t0[34]*w3 + t0[35]*w4 + t0[36]*w5
              + t0[68]*w6 + t0[69]*w7 + t0[70]*w8;
    float o = res ? (t0[35] + acc * scale + bias) : acc;
    out[(size_t)bc * 1024 + i] = o;
  }
}

// ---------------- LayerNorm over channel dim of (B, D, L) ----------------
__global__ void k_layernorm(const float* __restrict__ x, const float* __restrict__ lw,
                            const float* __restrict__ lb, float* __restrict__ xn) {
  int lane = threadIdx.x & 63;
  int slice = threadIdx.x >> 6;           // 4 slices of 96 channels
  int pos0 = blockIdx.x * 64;             // 64 positions, all same b
  int b = pos0 >> 10;
  int l = (pos0 & 1023) + lane;
  const float* xb = x + (size_t)b * DCH * LSP + l;
  float s = 0.f, s2 = 0.f;
  for (int d = slice * 96; d < slice * 96 + 96; d++) {
    float v = xb[(size_t)d * LSP];
    s += v; s2 += v * v;
  }
  __shared__ float red[2][4][64];
  red[0][slice][lane] = s; red[1][slice][lane] = s2;
  __syncthreads();
  if (slice == 0) {
    s  = red[0][0][lane] + red[0][1][lane] + red[0][2][lane] + red[0][3][lane];
    s2 = red[1][0][lane] + red[1][1][lane] + red[1][2][lane] + red[1][3][lane];
    float mu = s * (1.f / 384.f);
    float var = s2 * (1.f / 384.f) - mu * mu;
    red[0][0][lane] = mu;
    red[1][0][lane] = rsqrtf(var + 1e-5f);
  }
  __syncthreads();
  float mu = red[0][0][lane], rs = red[1][0][lane];
  float* xnb = xn + (size_t)b * DCH * LSP + l;
  for (int d = slice * 96; d < slice * 96 + 96; d++) {
    float v = xb[(size_t)d * LSP];
    xnb[(size_t)d * LSP] = (v - mu) * rs * lw[d] + lb[d];
  }
}

// ---- bcdt = bcdt_w(192x384) @ xn(b,384,1024), bf16 MFMA, 64x128 tiles ----
__global__ void __launch_bounds__(256) k_bcdt(
    const unsigned short* __restrict__ xnT, const unsigned short* __restrict__ wbc,
    float* __restrict__ out) {
  int lt = blockIdx.x, ct = blockIdx.y, b = blockIdx.z;   // (8, 3, 16)
  __shared__ unsigned short As[64 * 64];    // W tile (c rows)
  __shared__ unsigned short Bs[128 * 64];   // xnT tile (l rows)
  int tid = threadIdx.x;
  int lane = tid & 63, wave = tid >> 6;
  int wm = (wave & 1) * 32, wn = (wave >> 1) * 64;
  int fm = lane & 15, fq = lane >> 4;
  int srow = lane >> 3, slot = lane & 7;
  f32x4 acc[2][4];
  #pragma unroll
  for (int mi = 0; mi < 2; mi++)
    #pragma unroll
    for (int ni = 0; ni < 4; ni++) acc[mi][ni] = (f32x4)(0.f);
  const unsigned short* wge = wbc + (size_t)(ct * 64) * 384;
  const unsigned short* xge = xnT + ((size_t)(b * 1024 + lt * 128)) * 384;
  int ar0 = wave * 16 + srow, ar1 = ar0 + 8;
  const unsigned short* ag0 = wge + (size_t)ar0 * 384 + ((slot ^ (ar0 & 7)) * 8);
  const unsigned short* ag1 = wge + (size_t)ar1 * 384 + ((slot ^ (ar1 & 7)) * 8);
  const unsigned short* bg[4];
  #pragma unroll
  for (int ii = 0; ii < 4; ii++) {
    int brow = wave * 32 + ii * 8 + srow;
    bg[ii] = xge + (size_t)brow * 384 + ((slot ^ (brow & 7)) * 8);
  }
  unsigned short* asw0 = &As[(wave * 16) * 64];
  unsigned short* asw1 = &As[(wave * 16 + 8) * 64];
  for (int k0 = 0; k0 < 384; k0 += 64) {
    async16(ag0 + k0, asw0);
    async16(ag1 + k0, asw1);
    #pragma unroll
    for (int ii = 0; ii < 4; ii++)
      async16(bg[ii] + k0, &Bs[(wave * 32 + ii * 8) * 64]);
    __syncthreads();
    #pragma unroll
    for (int kk = 0; kk < 2; kk++) {
      int c = kk * 4 + fq;
      bf16x8 av[2];
      #pragma unroll
      for (int mi = 0; mi < 2; mi++) {
        int row = wm + mi * 16 + fm;
        av[mi] = *(bf16x8*)&As[row * 64 + ((c ^ (row & 7)) * 8)];
      }
      #pragma unroll
      for (int ni = 0; ni < 4; ni++) {
        int row = wn + ni * 16 + fm;
        bf16x8 bv = *(bf16x8*)&Bs[row * 64 + ((c ^ (row & 7)) * 8)];
        #pragma unroll
        for (int mi = 0; mi < 2; mi++)
          acc[mi][ni] = __builtin_amdgcn_mfma_f32_16x16x32_bf16(av[mi], bv, acc[mi][ni], 0, 0, 0);
      }
    }
    __syncthreads();
  }
  // C[m=c][n=l]: col (lane fm) -> l, coalesced fp32 stores
  float* ob = out + (size_t)b * 196608 + (size_t)(ct * 64) * 1024 + lt * 128;
  #pragma unroll
  for (int mi = 0; mi < 2; mi++)
    #pragma unroll
    for (int ni = 0; ni < 4; ni++)
      #pragma unroll
      for (int r = 0; r < 4; r++) {
        int row = wm + mi * 16 + fq * 4 + r;
        int col = wn + ni * 16 + fm;
        ob[(size_t)row * 1024 + col] = acc[mi][ni][r];
      }
}

// ---------------- softmax over L on dt rows (in place) ----------------
__global__ void k_softmax(float* __restrict__ bc, const float* __restrict__ Av) {
  int b = blockIdx.x >> 6, s = blockIdx.x & 63;
  float* row = bc + (size_t)b * 196608 + (size_t)(128 + s) * 1024;
  float a = Av[s];
  int t = threadIdx.x;
  float v[4]; float mx = -3.0e38f;
  #pragma unroll
  for (int i = 0; i < 4; i++) { v[i] = row[t + 256 * i] + a; mx = fmaxf(mx, v[i]); }
  #pragma unroll
  for (int off = 32; off >= 1; off >>= 1) mx = fmaxf(mx, __shfl_xor(mx, off));
  __shared__ float redm[4], reds[4];
  if ((t & 63) == 0) redm[t >> 6] = mx;
  __syncthreads();
  mx = fmaxf(fmaxf(redm[0], redm[1]), fmaxf(redm[2], redm[3]));
  float sm = 0.f;
  #pragma unroll
  for (int i = 0; i < 4; i++) { v[i] = __expf(v[i] - mx); sm += v[i]; }
  #pragma unroll
  for (int off = 32; off >= 1; off >>= 1) sm += __shfl_xor(sm, off);
  if ((t & 63) == 0) reds[t >> 6] = sm;
  __syncthreads();
  sm = reds[0] + reds[1] + reds[2] + reds[3];
  float inv = 1.f / sm;
  #pragma unroll
  for (int i = 0; i < 4; i++) row[t + 256 * i] = v[i] * inv;
}

// ---- h[b,d,s] += sum_{l in chunk} xn[b,d,l] * (Am*Bm)[b,s,l]; L split 8-way ----
__global__ void k_h(const float* __restrict__ xn, const float* __restrict__ bc,
                    float* __restrict__ h) {
  int dt_ = blockIdx.x, ls = blockIdx.y, b = blockIdx.z;   // (6, 8, 16)
  __shared__ float xs[64][65];
  __shared__ float ab[64][65];
  int tid = threadIdx.x;
  int sg4 = tid & 15, dg4 = tid >> 4;     // 16x16 thread grid, 4x4 regs each
  float acc[4][4];
  #pragma unroll
  for (int i = 0; i < 4; i++)
    #pragma unroll
    for (int j = 0; j < 4; j++) acc[i][j] = 0.f;
  const float* Bm = bc + (size_t)b * 196608;
  const float* Am = Bm + 131072;
  const float* xb = xn + (size_t)b * DCH * LSP + (size_t)(dt_ * 64) * LSP;
  for (int l0 = ls * 128; l0 < ls * 128 + 128; l0 += 64) {
    for (int i = tid; i < 4096; i += 256) {
      int r = i >> 6, ll = i & 63;
      xs[r][ll] = xb[(size_t)r * LSP + l0 + ll];
      ab[r][ll] = Am[(size_t)r * 1024 + l0 + ll] * Bm[(size_t)r * 1024 + l0 + ll];
    }
    __syncthreads();
    for (int ll = 0; ll < 64; ll++) {
      float xv[4], av[4];
      #pragma unroll
      for (int i = 0; i < 4; i++) xv[i] = xs[dg4 * 4 + i][ll];
      #pragma unroll
      for (int j = 0; j < 4; j++) av[j] = ab[sg4 * 4 + j][ll];
      #pragma unroll
      for (int i = 0; i < 4; i++)
        #pragma unroll
        for (int j = 0; j < 4; j++) acc[i][j] += xv[i] * av[j];
    }
    __syncthreads();
  }
  float* hb = h + (size_t)b * DCH * SST + (size_t)(dt_ * 64) * 64;
  #pragma unroll
  for (int i = 0; i < 4; i++)
    #pragma unroll
    for (int j = 0; j < 4; j++)
      atomicAdd(&hb[(size_t)(dg4 * 4 + i) * 64 + sg4 * 4 + j], acc[i][j]);
}

// ---- hpre[b,e,s] += sum_{d in chunk} pw[e,d]*h[b,d,s]; K split 3-way ----
__global__ void k_hproj(const float* __restrict__ h, const float* __restrict__ pw,
                        float* __restrict__ hpre) {
  int et = blockIdx.x, ks = blockIdx.y, b = blockIdx.z;   // (6, 3, 16)
  __shared__ float hs[64][65];   // [d][s]
  __shared__ float ps[64][65];   // [e][d]
  int tid = threadIdx.x;
  int sg4 = tid & 15, eg4 = tid >> 4;
  float acc[4][4];
  #pragma unroll
  for (int i = 0; i < 4; i++)
    #pragma unroll
    for (int j = 0; j < 4; j++) acc[i][j] = 0.f;
  for (int d0 = ks * 128; d0 < ks * 128 + 128; d0 += 64) {
    for (int i = tid; i < 4096; i += 256) {
      int r = i >> 6, cc = i & 63;
      hs[r][cc] = h[(size_t)b * DCH * SST + (size_t)(d0 + r) * 64 + cc];
      ps[r][cc] = pw[(size_t)(et * 64 + r) * 384 + d0 + cc];
    }
    __syncthreads();
    for (int dd = 0; dd < 64; dd++) {
      float pv[4], hv[4];
      #pragma unroll
      for (int i = 0; i < 4; i++) pv[i] = ps[eg4 * 4 + i][dd];
      #pragma unroll
      for (int j = 0; j < 4; j++) hv[j] = hs[dd][sg4 * 4 + j];
      #pragma unroll
      for (int i = 0; i < 4; i++)
        #pragma unroll
        for (int j = 0; j < 4; j++) acc[i][j] += pv[i] * hv[j];
    }
    __syncthreads();
  }
  float* hb = hpre + (size_t)b * DCH * SST + (size_t)(et * 64) * 64;
  #pragma unroll
  for (int i = 0; i < 4; i++)
    #pragma unroll
    for (int j = 0; j < 4; j++)
      atomicAdd(&hb[(size_t)(eg4 * 4 + i) * 64 + sg4 * 4 + j], acc[i][j]);
}

// ---- h2 = silu(hpre), vectorized ----
__global__ void k_silu(const float* __restrict__ hpre, float* __restrict__ h2) {
  int i = blockIdx.x * 256 + threadIdx.x;   // over 98304 float4s
  float4 v = ((const float4*)hpre)[i];
  v.x = v.x / (1.f + __expf(-v.x));
  v.y = v.y / (1.f + __expf(-v.y));
  v.z = v.z / (1.f + __expf(-v.z));
  v.w = v.w / (1.f + __expf(-v.w));
  ((float4*)h2)[i] = v;
}

// ---------------- x2 = x1 + h2 @ Cm ----------------
__global__ void k_y(const float* __restrict__ h2, const float* __restrict__ bc,
                    const float* __restrict__ x1, float* __restrict__ x2) {
  int lt = blockIdx.x, dt_ = blockIdx.y, b = blockIdx.z;   // (8, 12, 16)
  __shared__ float hss[32][65];
  __shared__ float cs[64][129];
  int lg = threadIdx.x & 31, dg = threadIdx.x >> 5;
  float acc[4][4];
  for (int i = 0; i < 4; i++) for (int j = 0; j < 4; j++) acc[i][j] = 0.f;
  for (int i = threadIdx.x; i < 2048; i += 256) {
    int r = i >> 6, cc = i & 63;
    hss[r][cc] = h2[(size_t)b * DCH * SST + (size_t)(dt_ * 32 + r) * 64 + cc];
  }
  const float* Cm = bc + (size_t)b * 196608 + 65536;
  for (int i = threadIdx.x; i < 8192; i += 256) {
    int ss = i >> 7, ll = i & 127;
    cs[ss][ll] = Cm[(size_t)ss * 1024 + lt * 128 + ll];
  }
  __syncthreads();
  for (int ss = 0; ss < 64; ss++) {
    float cv[4];
    #pragma unroll
    for (int il = 0; il < 4; il++) cv[il] = cs[ss][lg + 32 * il];
    #pragma unroll
    for (int id = 0; id < 4; id++) {
      float hv = hss[dg * 4 + id][ss];
      #pragma unroll
      for (int il = 0; il < 4; il++) acc[id][il] += hv * cv[il];
    }
  }
  size_t base = (size_t)b * DCH * LSP + (size_t)(dt_ * 32) * LSP + lt * 128;
  for (int id = 0; id < 4; id++)
    for (int il = 0; il < 4; il++) {
      size_t o = base + (size_t)(dg * 4 + id) * LSP + lg + 32 * il;
      x2[o] = x1[o] + acc[id][il];
    }
}

// ---------------- router logits ----------------
__global__ void k_router(const float* __restrict__ x3, const float* __restrict__ gw,
                         const float* __restrict__ gb, float* __restrict__ logits) {
  __shared__ float xs[64][65];
  __shared__ float gs[8][64];
  int blk = blockIdx.x;                  // 256 blocks of 64 tokens
  int b = blk >> 4; int l0 = (blk & 15) * 64;
  int lg = threadIdx.x & 63, eg = threadIdx.x >> 6;
  float acc0 = 0.f, acc1 = 0.f;
  const float* xb = x3 + (size_t)b * DCH * LSP + l0;
  for (int d0 = 0; d0 < 384; d0 += 64) {
    for (int i = threadIdx.x; i < 4096; i += 256) {
      int dd = i >> 6, ll = i & 63;
      xs[dd][ll] = xb[(size_t)(d0 + dd) * LSP + ll];
    }
    for (int i = threadIdx.x; i < 512; i += 256) {
      int e = i >> 6, dd = i & 63;
      gs[e][dd] = gw[(size_t)e * 384 + d0 + dd];
    }
    __syncthreads();
    for (int dd = 0; dd < 64; dd++) {
      float xv = xs[dd][lg];
      acc0 += gs[eg][dd] * xv;
      acc1 += gs[eg + 4][dd] * xv;
    }
    __syncthreads();
  }
  int n = b * 1024 + l0 + lg;
  logits[(size_t)n * 8 + eg]     = acc0 + gb[eg];
  logits[(size_t)n * 8 + eg + 4] = acc1 + gb[eg + 4];
}

// ---------------- top-2 + softmax + counts (LDS-aggregated atomics) ----------------
__global__ void k_topk(const float* __restrict__ logits, float* __restrict__ probs,
                       int* __restrict__ idx, int* __restrict__ cnt) {
  __shared__ int lcnt[8];
  if (threadIdx.x < 8) lcnt[threadIdx.x] = 0;
  __syncthreads();
  int n = blockIdx.x * 256 + threadIdx.x;
  float lv[8];
  for (int e = 0; e < 8; e++) lv[e] = logits[(size_t)n * 8 + e];
  int i1 = 0; float v1 = lv[0];
  for (int e = 1; e < 8; e++) if (lv[e] > v1) { v1 = lv[e]; i1 = e; }
  int i2 = -1; float v2 = -3.0e38f;
  for (int e = 0; e < 8; e++) { if (e == i1) continue; if (lv[e] > v2) { v2 = lv[e]; i2 = e; } }
  float p1 = 1.f / (1.f + __expf(v2 - v1));
  probs[n * 2] = p1; probs[n * 2 + 1] = 1.f - p1;
  idx[n * 2] = i1; idx[n * 2 + 1] = i2;
  atomicAdd(&lcnt[i1], 1); atomicAdd(&lcnt[i2], 1);
  __syncthreads();
  if (threadIdx.x < 8) atomicAdd(&cnt[threadIdx.x], lcnt[threadIdx.x]);
}

__global__ void k_offsets(const int* __restrict__ cnt, int* __restrict__ offs,
                          int* __restrict__ toff) {
  if (threadIdx.x == 0) {
    int a = 0, t = 0;
    for (int e = 0; e < 8; e++) {
      offs[e] = a; toff[e] = t;
      a += cnt[e]; t += (cnt[e] + 63) >> 6;
    }
    toff[8] = t;
  }
}

// ---------------- build expert token lists (LDS-aggregated) ----------------
__global__ void k_build(const int* __restrict__ idx, const float* __restrict__ probs,
                        const int* __restrict__ offs, int* __restrict__ fill,
                        int* __restrict__ ltok, float* __restrict__ lp,
                        int* __restrict__ tpos) {
  __shared__ int lcnt[8], lbase[8];
  if (threadIdx.x < 8) lcnt[threadIdx.x] = 0;
  __syncthreads();
  int n = blockIdx.x * 256 + threadIdx.x;
  int e0 = idx[n * 2], e1 = idx[n * 2 + 1];
  int o0 = atomicAdd(&lcnt[e0], 1);
  int o1 = atomicAdd(&lcnt[e1], 1);
  __syncthreads();
  if (threadIdx.x < 8) lbase[threadIdx.x] = atomicAdd(&fill[threadIdx.x], lcnt[threadIdx.x]);
  __syncthreads();
  int p0 = offs[e0] + lbase[e0] + o0;
  int p1 = offs[e1] + lbase[e1] + o1;
  ltok[p0] = n; lp[p0] = probs[n * 2];     tpos[n * 2] = p0;
  ltok[p1] = n; lp[p1] = probs[n * 2 + 1]; tpos[n * 2 + 1] = p1;
}

// ---------------- fp32 [D][L] -> bf16 [N][D] transpose ----------------
__global__ void k_t16(const float* __restrict__ x3, unsigned short* __restrict__ t16) {
  __shared__ float tl[32][33];
  int lt = blockIdx.x, dt_ = blockIdx.y, b = blockIdx.z;   // (32, 12, 16)
  const float* xb = x3 + (size_t)b * DCH * LSP + (size_t)(dt_ * 32) * LSP + lt * 32;
  for (int i = threadIdx.x; i < 1024; i += 256) {
    int dd = i >> 5, ll = i & 31;
    tl[dd][ll] = xb[(size_t)dd * LSP + ll];
  }
  __syncthreads();
  for (int i = threadIdx.x; i < 1024; i += 256) {
    int ll = i >> 5, dd = i & 31;
    int n = b * 1024 + lt * 32 + ll;
    t16[(size_t)n * 384 + dt_ * 32 + dd] = f2bf(tl[dd][ll]);
  }
}

// ---------------- bcdt_w fp32 -> bf16 (73728 elems = 18432 float4) ----------------
__global__ void k_wbf(const float* __restrict__ s, unsigned short* __restrict__ d) {
  int i = blockIdx.x * 256 + threadIdx.x;
  float4 v = ((const float4*)s)[i];
  u16x4 o;
  o.x = f2bf(v.x); o.y = f2bf(v.y); o.z = f2bf(v.z); o.w = f2bf(v.w);
  ((u16x4*)d)[i] = o;
}

// ---------------- 3 weight arrays fp32 -> bf16, vectorized ----------------
__global__ void k_f2bf3(const float* __restrict__ s0, const float* __restrict__ s1,
                        const float* __restrict__ s2, unsigned short* __restrict__ d0,
                        unsigned short* __restrict__ d1, unsigned short* __restrict__ d2,
                        int n4) {
  int i = blockIdx.x * 256 + threadIdx.x;
  if (i >= n4) return;
  const float* s = (blockIdx.y == 0) ? s0 : (blockIdx.y == 1) ? s1 : s2;
  unsigned short* d = (blockIdx.y == 0) ? d0 : (blockIdx.y == 1) ? d1 : d2;
  float4 v = ((const float4*)s)[i];
  u16x4 o;
  o.x = f2bf(v.x); o.y = f2bf(v.y); o.z = f2bf(v.z); o.w = f2bf(v.w);
  ((u16x4*)d)[i] = o;
}

// ---- MoE GEMM1: he = silu(t@w1^T+b1)*(t@w3^T+b3); 64x128 tile, BK=64,
//      XOR-swizzled LDS, async global_load_lds staging ----
__global__ void __launch_bounds__(256) k_moe1(
    const unsigned short* __restrict__ t16, const unsigned short* __restrict__ w1,
    const unsigned short* __restrict__ w3, const float* __restrict__ b1,
    const float* __restrict__ b3, const int* __restrict__ ltok,
    const int* __restrict__ cnt, const int* __restrict__ offs,
    const int* __restrict__ toff, unsigned short* __restrict__ he) {
  int tb = blockIdx.x;
  if (tb >= toff[8]) return;
  int e = 0;
  #pragma unroll
  for (int i = 1; i < 8; i++) if (toff[i] <= tb) e = i;
  int rt = tb - toff[e];
  int ne = cnt[e], base = offs[e];
  int ct = blockIdx.y;                  // 6 col tiles of 128 over HID
  __shared__ unsigned short As[64 * 64];     // 8 KB
  __shared__ unsigned short B1s[128 * 64];   // 16 KB
  __shared__ unsigned short B3s[128 * 64];   // 16 KB
  __shared__ int toks[64];
  int tid = threadIdx.x;
  if (tid < 64) {
    int r = rt * 64 + tid;
    toks[tid] = ltok[base + (r < ne ? r : ne - 1)];
  }
  __syncthreads();
  int lane = tid & 63, wave = tid >> 6;
  int wm = (wave & 1) * 32, wn = (wave >> 1) * 64;
  int fm = lane & 15, fq = lane >> 4;
  int srow = lane >> 3, slot = lane & 7;
  f32x4 acc1[2][4], acc3[2][4];
  #pragma unroll
  for (int mi = 0; mi < 2; mi++)
    #pragma unroll
    for (int ni = 0; ni < 4; ni++) { acc1[mi][ni] = (f32x4)(0.f); acc3[mi][ni] = (f32x4)(0.f); }
  const unsigned short* w1e = w1 + ((size_t)e * 768 + ct * 128) * 384;
  const unsigned short* w3e = w3 + ((size_t)e * 768 + ct * 128) * 384;
  int ar0 = wave * 16 + srow, ar1 = wave * 16 + 8 + srow;
  const unsigned short* ag0 = t16 + (size_t)toks[ar0] * 384 + ((slot ^ (ar0 & 7)) * 8);
  const unsigned short* ag1 = t16 + (size_t)toks[ar1] * 384 + ((slot ^ (ar1 & 7)) * 8);
  const unsigned short* b1g[4]; const unsigned short* b3g[4];
  #pragma unroll
  for (int ii = 0; ii < 4; ii++) {
    int brow = wave * 32 + ii * 8 + srow;
    int coff = (slot ^ (brow & 7)) * 8;
    b1g[ii] = w1e + (size_t)brow * 384 + coff;
    b3g[ii] = w3e + (size_t)brow * 384 + coff;
  }
  unsigned short* asw0 = &As[(wave * 16) * 64];
  unsigned short* asw1 = &As[(wave * 16 + 8) * 64];
  for (int k0 = 0; k0 < 384; k0 += 64) {
    async16(ag0 + k0, asw0);
    async16(ag1 + k0, asw1);
    #pragma unroll
    for (int ii = 0; ii < 4; ii++) {
      async16(b1g[ii] + k0, &B1s[(wave * 32 + ii * 8) * 64]);
      async16(b3g[ii] + k0, &B3s[(wave * 32 + ii * 8) * 64]);
    }
    __syncthreads();
    #pragma unroll
    for (int kk = 0; kk < 2; kk++) {
      int c = kk * 4 + fq;
      bf16x8 av[2];
      #pragma unroll
      for (int mi = 0; mi < 2; mi++) {
        int row = wm + mi * 16 + fm;
        av[mi] = *(bf16x8*)&As[row * 64 + ((c ^ (row & 7)) * 8)];
      }
      #pragma unroll
      for (int ni = 0; ni < 4; ni++) {
        int row = wn + ni * 16 + fm;
        int off = row * 64 + ((c ^ (row & 7)) * 8);
        bf16x8 b1v = *(bf16x8*)&B1s[off];
        bf16x8 b3v = *(bf16x8*)&B3s[off];
        #pragma unroll
        for (int mi = 0; mi < 2; mi++) {
          acc1[mi][ni] = __builtin_amdgcn_mfma_f32_16x16x32_bf16(av[mi], b1v, acc1[mi][ni], 0, 0, 0);
          acc3[mi][ni] = __builtin_amdgcn_mfma_f32_16x16x32_bf16(av[mi], b3v, acc3[mi][ni], 0, 0, 0);
        }
      }
    }
    __syncthreads();
  }
  #pragma unroll
  for (int mi = 0; mi < 2; mi++)
    #pragma unroll
    for (int ni = 0; ni < 4; ni++)
      #pragma unroll
      for (int r = 0; r < 4; r++) {
        int lr = wm + mi * 16 + fq * 4 + r;
        int gr = rt * 64 + lr;
        if (gr < ne) {
          int col = ct * 128 + wn + ni * 16 + fm;
          float z1 = acc1[mi][ni][r] + b1[e * 768 + col];
          float z3 = acc3[mi][ni][r] + b3[e * 768 + col];
          float val = (z1 / (1.f + __expf(-z1))) * z3;
          he[((size_t)base + gr) * 768 + col] = f2bf(val);
        }
      }
}

// ---- MoE GEMM2: ymoe[pos][col] = (he@w2^T + b2) * lp; same structure, K=768 ----
__global__ void __launch_bounds__(256) k_moe2(
    const unsigned short* __restrict__ he, const unsigned short* __restrict__ w2,
    const float* __restrict__ b2, const float* __restrict__ lp,
    const int* __restrict__ cnt, const int* __restrict__ offs,
    const int* __restrict__ toff, unsigned short* __restrict__ ymoe) {
  int tb = blockIdx.x;
  if (tb >= toff[8]) return;
  int e = 0;
  #pragma unroll
  for (int i = 1; i < 8; i++) if (toff[i] <= tb) e = i;
  int rt = tb - toff[e];
  int ne = cnt[e], base = offs[e];
  int ct = blockIdx.y;                  // 3 col tiles of 128 over D
  __shared__ unsigned short As[64 * 64];    // 8 KB
  __shared__ unsigned short Bs[128 * 64];   // 16 KB
  __shared__ float lps[64];
  int tid = threadIdx.x;
  if (tid < 64) {
    int r = rt * 64 + tid;
    lps[tid] = lp[base + (r < ne ? r : ne - 1)];
  }
  int lane = tid & 63, wave = tid >> 6;
  int wm = (wave & 1) * 32, wn = (wave >> 1) * 64;
  int fm = lane & 15, fq = lane >> 4;
  int srow = lane >> 3, slot = lane & 7;
  f32x4 acc[2][4];
  #pragma unroll
  for (int mi = 0; mi < 2; mi++)
    #pragma unroll
    for (int ni = 0; ni < 4; ni++) acc[mi][ni] = (f32x4)(0.f);
  const unsigned short* w2e = w2 + ((size_t)e * 384 + ct * 128) * 768;
  int ar0 = wave * 16 + srow, ar1 = wave * 16 + 8 + srow;
  int g0 = base + rt * 64 + ar0; if (g0 > 32767) g0 = 32767;
  int g1 = base + rt * 64 + ar1; if (g1 > 32767) g1 = 32767;
  const unsigned short* ag0 = he + (size_t)g0 * 768 + ((slot ^ (ar0 & 7)) * 8);
  const unsigned short* ag1 = he + (size_t)g1 * 768 + ((slot ^ (ar1 & 7)) * 8);
  const unsigned short* bg[4];
  #pragma unroll
  for (int ii = 0; ii < 4; ii++) {
    int brow = wave * 32 + ii * 8 + srow;
    bg[ii] = w2e + (size_t)brow * 768 + ((slot ^ (brow & 7)) * 8);
  }
  unsigned short* asw0 = &As[(wave * 16) * 64];
  unsigned short* asw1 = &As[(wave * 16 + 8) * 64];
  for (int k0 = 0; k0 < 768; k0 += 64) {
    async16(ag0 + k0, asw0);
    async16(ag1 + k0, asw1);
    #pragma unroll
    for (int ii = 0; ii < 4; ii++)
      async16(bg[ii] + k0, &Bs[(wave * 32 + ii * 8) * 64]);
    __syncthreads();
    #pragma unroll
    for (int kk = 0; kk < 2; kk++) {
      int c = kk * 4 + fq;
      bf16x8 av[2];
      #pragma unroll
      for (int mi = 0; mi < 2; mi++) {
        int row = wm + mi * 16 + fm;
        av[mi] = *(bf16x8*)&As[row * 64 + ((c ^ (row & 7)) * 8)];
      }
      #pragma unroll
      for (int ni = 0; ni < 4; ni++) {
        int row = wn + ni * 16 + fm;
        bf16x8 bv = *(bf16x8*)&Bs[row * 64 + ((c ^ (row & 7)) * 8)];
        #pragma unroll
        for (int mi = 0; mi < 2; mi++)
          acc[mi][ni] = __builtin_amdgcn_mfma_f32_16x16x32_bf16(av[mi], bv, acc[mi][ni], 0, 0, 0);
      }
    }
    __syncthreads();
  }
  #pragma unroll
  for (int mi = 0; mi < 2; mi++)
    #pragma unroll
    for (int ni = 0; ni < 4; ni++)
      #pragma unroll
      for (int r = 0; r < 4; r++) {
        int lr = wm + mi * 16 + fq * 4 + r;
        int gr = rt * 64 + lr;
        if (gr < ne) {
          int col = ct * 128 + wn + ni * 16 + fm;
          float val = (acc[mi][ni][r] + b2[e * 384 + col]) * lps[lr];
          ymoe[((size_t)base + gr) * 384 + col] = f2bf(val);
        }
      }
}

// ---- gather each token's two ymoe rows, add into xout (transposed layout) ----
__global__ void k_scatter(const unsigned short* __restrict__ ymoe,
                          const int* __restrict__ tpos, float* __restrict__ xout) {
  int dt_ = blockIdx.x;  // 12 tiles of 32 d
  int lt = blockIdx.y;   // 16 tiles of 64 l
  int b = blockIdx.z;    // 16
  int l = threadIdx.x & 63;
  int d0 = dt_ * 32 + (threadIdx.x >> 6) * 8;
  int n = b * 1024 + lt * 64 + l;
  int p0 = tpos[2 * n], p1 = tpos[2 * n + 1];
  bf16x8 y0 = *(const bf16x8*)(ymoe + (size_t)p0 * 384 + d0);
  bf16x8 y1 = *(const bf16x8*)(ymoe + (size_t)p1 * 384 + d0);
  size_t base = (size_t)b * DCH * LSP + (size_t)d0 * LSP + lt * 64 + l;
  #pragma unroll
  for (int k = 0; k < 8; k++) {
    float v = bf2f((unsigned short)y0[k]) + bf2f((unsigned short)y1[k]);
    xout[base + (size_t)k * LSP] += v;
  }
}

extern "C" void kernel_launch(void* const* d_in, const int* in_sizes, int n_in,
                              void* d_out, int out_size, void* d_ws, size_t ws_size,
                              hipStream_t stream) {
  const float* x      = (const float*)d_in[0];
  const float* dw1    = (const float*)d_in[1];
  const float* bn1g   = (const float*)d_in[2];
  const float* bn1b   = (const float*)d_in[3];
  const float* bn1m   = (const float*)d_in[4];
  const float* bn1v   = (const float*)d_in[5];
  const float* dw2    = (const float*)d_in[6];
  const float* bn2g   = (const float*)d_in[7];
  const float* bn2b   = (const float*)d_in[8];
  const float* bn2m   = (const float*)d_in[9];
  const float* bn2v   = (const float*)d_in[10];
  const float* lnw    = (const float*)d_in[11];
  const float* lnb    = (const float*)d_in[12];
  const float* bcdtw  = (const float*)d_in[13];
  const float* dwsw   = (const float*)d_in[14];
  const float* hprojw = (const float*)d_in[15];
  const float* Avec   = (const float*)d_in[16];
  const float* gatew  = (const float*)d_in[17];
  const float* gateb  = (const float*)d_in[18];
  const float* w1f    = (const float*)d_in[19];
  const float* b1f    = (const float*)d_in[20];
  const float* w2f    = (const float*)d_in[21];
  const float* b2f    = (const float*)d_in[22];
  const float* w3f    = (const float*)d_in[23];
  const float* b3f    = (const float*)d_in[24];

  char* wsb = (char*)d_ws;
  float* x1    = (float*)(wsb + OFF_X1);
  float* xn    = (float*)(wsb + OFF_XN);
  float* bcdt  = (float*)(wsb + OFF_BCDT);
  float* bcdtc = (float*)(wsb + OFF_BCDTC);
  float* hbuf  = (float*)(wsb + OFF_H);
  float* hpre  = (float*)(wsb + OFF_HPRE);
  float* x2    = (float*)(wsb + OFF_X2);
  float* logits = (float*)(wsb + OFF_LOGITS);
  float* probs  = (float*)(wsb + OFF_PROBS);
  int*   idx    = (int*)(wsb + OFF_IDX);
  int*   cnt    = (int*)(wsb + OFF_CNT);
  int*   fill   = (int*)(wsb + OFF_FILL);
  int*   offs   = (int*)(wsb + OFF_OFFS);
  int*   toff   = (int*)(wsb + OFF_TOFF);
  int*   ltok   = (int*)(wsb + OFF_LTOK);
  float* lp     = (float*)(wsb + OFF_LP);
  int*   tpos   = (int*)(wsb + OFF_TPOS);
  unsigned short* t16  = (unsigned short*)(wsb + OFF_T16);
  unsigned short* w1b  = (unsigned short*)(wsb + OFF_W1B);
  unsigned short* w3b  = (unsigned short*)(wsb + OFF_W3B);
  unsigned short* w2b  = (unsigned short*)(wsb + OFF_W2B);
  unsigned short* he   = (unsigned short*)(wsb + OFF_HE);
  unsigned short* ymoe = (unsigned short*)(wsb + OFF_YMOE);
  unsigned short* xnT  = (unsigned short*)(wsb + OFF_XNT);
  unsigned short* wbc  = (unsigned short*)(wsb + OFF_WBC);
  float* xout = (float*)d_out;
  float* h2   = xout + (size_t)BSZ * DCH * LSP;   // second output region

  // stage 1: x1 = x + bn1(dw1(x))
  k_dwbnres<<<BSZ * DCH, 256, 0, stream>>>(x, dw1, bn1g, bn1b, bn1m, bn1v, x1, DCH);
  // stage 2: layernorm -> xn
  k_layernorm<<<NTOK / 64, 256, 0, stream>>>(x1, lnw, lnb, xn);
  // stage 2.5: xn -> xnT bf16 [l][d]; bcdt_w -> bf16
  k_t16<<<dim3(32, 12, BSZ), 256, 0, stream>>>(xn, xnT);
  k_wbf<<<72, 256, 0, stream>>>(bcdtw, wbc);
  // stage 3: bcdt = bcdt_w @ xn (bf16 MFMA)
  k_bcdt<<<dim3(8, 3, BSZ), 256, 0, stream>>>(xnT, wbc, bcdt);
  // stage 4: depthwise conv on bcdt
  k_dwbnres<<<BSZ * 192, 256, 0, stream>>>(bcdt, dwsw, nullptr, nullptr, nullptr, nullptr, bcdtc, 192);
  // stage 5: softmax(dt + A) over L
  k_softmax<<<BSZ * SST, 256, 0, stream>>>(bcdtc, Avec);
  // zero accumulators for split-K stages
  hipMemsetAsync(hbuf, 0, (size_t)BSZ * DCH * SST * 4, stream);
  hipMemsetAsync(hpre, 0, (size_t)BSZ * DCH * SST * 4, stream);
  // stage 6: h = xn @ (Am*Bm)^T  (L split 8-way, atomic accumulate)
  k_h<<<dim3(6, 8, BSZ), 256, 0, stream>>>(xn, bcdtc, hbuf);
  // stage 7: hpre = hproj @ h (K split 3-way, atomic), then h2 = silu(hpre)
  k_hproj<<<dim3(6, 3, BSZ), 256, 0, stream>>>(hbuf, hprojw, hpre);
  k_silu<<<(BSZ * DCH * SST / 4) / 256, 256, 0, stream>>>(hpre, h2);
  // stage 8: x2 = x1 + h2 @ Cm
  k_y<<<dim3(8, 12, BSZ), 256, 0, stream>>>(h2, bcdtc, x1, x2);
  // stage 9: x3 = x2 + bn2(dw2(x2)) -> d_out
  k_dwbnres<<<BSZ * DCH, 256, 0, stream>>>(x2, dw2, bn2g, bn2b, bn2m, bn2v, xout, DCH);
  // MoE routing
  hipMemsetAsync(wsb + OFF_CNT, 0, 64, stream);   // cnt + fill
  k_router<<<256, 256, 0, stream>>>(xout, gatew, gateb, logits);
  k_topk<<<NTOK / 256, 256, 0, stream>>>(logits, probs, idx, cnt);
  k_offsets<<<1, 64, 0, stream>>>(cnt, offs, toff);
  k_build<<<NTOK / 256, 256, 0, stream>>>(idx, probs, offs, fill, ltok, lp, tpos);
  // tokens + weights to bf16
  k_t16<<<dim3(32, 12, BSZ), 256, 0, stream>>>(xout, t16);
  int n4 = NEXP * HID * DCH / 4;
  k_f2bf3<<<dim3((n4 + 255) / 256, 3), 256, 0, stream>>>(w1f, w3f, w2f, w1b, w3b, w2b, n4);
  // MoE GEMMs: single launch each, flat (expert,row-tile) index
  k_moe1<<<dim3(MOE_MAXT, 6), 256, 0, stream>>>(t16, w1b, w3b, b1f, b3f, ltok, cnt, offs, toff, he);
  k_moe2<<<dim3(MOE_MAXT, 3), 256, 0, stream>>>(he, w2b, b2f, lp, cnt, offs, toff, ymoe);
  // gather + residual add
  k_scatter<<<dim3(12, 16, BSZ), 256, 0, stream>>>(ymoe, tpos, xout);
}